// Round 13
// baseline (811.142 us; speedup 1.0000x reference)
//
#include <hip/hip_runtime.h>
#include <hip/hip_fp16.h>

#define L_SZ 2048
#define VCAB 32000
#define GRU_WGS 8
#define NGRP 32
#define CHUNK 64
#define WARM 128
#define PF 12
#define RING 16

typedef __attribute__((ext_vector_type(8))) _Float16 f16x8;
typedef __attribute__((ext_vector_type(4))) float f32x4;

// ---------------- f32 -> f16 conversion (4 elems/thread) ----------------
__global__ __launch_bounds__(256) void conv_f16_kernel(const float* __restrict__ in,
                                                       __half* __restrict__ out, int n4) {
  int i = blockIdx.x * 256 + threadIdx.x;
  if (i >= n4) return;
  float4 v = ((const float4*)in)[i];
  __half2 a = __floats2half2_rn(v.x, v.y);
  __half2 b = __floats2half2_rn(v.z, v.w);
  uint2 u;
  u.x = *(unsigned*)&a;
  u.y = *(unsigned*)&b;
  ((uint2*)out)[i] = u;
}

// ---------------- prep: Wcat=[wq;wk;wh] f16 + biascat=[bq;bk;bh] f32, one launch ----------------
__global__ __launch_bounds__(256) void prep_kernel(const float* __restrict__ wq,
                                                   const float* __restrict__ wk,
                                                   const float* __restrict__ wh,
                                                   const float* __restrict__ bq,
                                                   const float* __restrict__ bk,
                                                   const float* __restrict__ bh,
                                                   __half* __restrict__ Wcat,
                                                   float* __restrict__ biascat) {
  int idx = blockIdx.x * 256 + threadIdx.x;   // 0..65535 (512*512/4)
  int e = idx * 4;
  int row = e >> 9, col = e & 511;
  const float* src = (row < 128) ? &wq[row * 512 + col]
                   : (row < 256) ? &wk[(row - 128) * 512 + col]
                                 : &wh[(row - 256) * 512 + col];
  float4 v = *(const float4*)src;
  __half2 a = __floats2half2_rn(v.x, v.y);
  __half2 b = __floats2half2_rn(v.z, v.w);
  uint2 u;
  u.x = *(unsigned*)&a;
  u.y = *(unsigned*)&b;
  ((uint2*)Wcat)[idx] = u;
  if (idx < 512)
    biascat[idx] = (idx < 128) ? bq[idx] : (idx < 256) ? bk[idx - 128] : bh[idx - 256];
}

// ---------------- generic MFMA GEMM, global_load_lds staging, XCD-swizzled ----------------
// C[m][n] = bias[n] + A_f16[row(m)] . W_f16[n]; A row stride lda; W row stride K.
__global__ __launch_bounds__(256) void mfma_gemm_kernel(const __half* __restrict__ A,
                                                        const __half* __restrict__ W,
                                                        const float* __restrict__ bias,
                                                        float* __restrict__ C,
                                                        __half* __restrict__ C16,
                                                        int M, int N, int K, int lda, int ldc,
                                                        const int* __restrict__ gather) {
  __shared__ __align__(16) __half Al[128 * 32];
  __shared__ __align__(16) __half Wl[128 * 32];
  const int tid = threadIdx.x;
  const int nbx = gridDim.x;
  int flat = blockIdx.y * nbx + blockIdx.x;
  int cpx = (nbx * gridDim.y) >> 3;
  int swz = (flat & 7) * cpx + (flat >> 3);
  const int n0 = (swz % nbx) * 128, m0 = (swz / nbx) * 128;
  const int lane = tid & 63, wave = tid >> 6;
  const int wm = wave >> 1, wn = wave & 1;
  const int fr = lane & 15, fk = (lane >> 4) * 8;
  const int r0 = tid >> 2, q0 = tid & 3;
  const int r1 = (tid + 256) >> 2, q1 = tid & 3;
  const int arow0 = gather ? gather[m0 + r0] : (m0 + r0);
  const int arow1 = gather ? gather[m0 + r1] : (m0 + r1);
  __half* a0d = &Al[wave * 512];
  __half* a1d = &Al[wave * 512 + 2048];
  __half* w0d = &Wl[wave * 512];
  __half* w1d = &Wl[wave * 512 + 2048];

  f32x4 acc[4][4];
#pragma unroll
  for (int i = 0; i < 4; ++i)
#pragma unroll
    for (int j = 0; j < 4; ++j) acc[i][j] = (f32x4){0.f, 0.f, 0.f, 0.f};

  for (int kt = 0; kt < K; kt += 32) {
    __builtin_amdgcn_global_load_lds((const unsigned int*)(A + (size_t)arow0 * lda + kt + q0 * 8),
                                     (unsigned int*)a0d, 16, 0, 0);
    __builtin_amdgcn_global_load_lds((const unsigned int*)(A + (size_t)arow1 * lda + kt + q1 * 8),
                                     (unsigned int*)a1d, 16, 0, 0);
    __builtin_amdgcn_global_load_lds((const unsigned int*)(W + (size_t)(n0 + r0) * K + kt + q0 * 8),
                                     (unsigned int*)w0d, 16, 0, 0);
    __builtin_amdgcn_global_load_lds((const unsigned int*)(W + (size_t)(n0 + r1) * K + kt + q1 * 8),
                                     (unsigned int*)w1d, 16, 0, 0);
    __syncthreads();
    f16x8 af[4], bfv[4];
#pragma unroll
    for (int mf = 0; mf < 4; ++mf) af[mf] = *(const f16x8*)&Al[(wm * 64 + mf * 16 + fr) * 32 + fk];
#pragma unroll
    for (int nf = 0; nf < 4; ++nf) bfv[nf] = *(const f16x8*)&Wl[(wn * 64 + nf * 16 + fr) * 32 + fk];
#pragma unroll
    for (int mf = 0; mf < 4; ++mf)
#pragma unroll
      for (int nf = 0; nf < 4; ++nf)
        acc[mf][nf] = __builtin_amdgcn_mfma_f32_16x16x32_f16(af[mf], bfv[nf], acc[mf][nf], 0, 0, 0);
    __syncthreads();
  }
  const int r4 = (lane >> 4) * 4;
#pragma unroll
  for (int mf = 0; mf < 4; ++mf)
#pragma unroll
    for (int nf = 0; nf < 4; ++nf)
#pragma unroll
      for (int v = 0; v < 4; ++v) {
        int m = m0 + wm * 64 + mf * 16 + r4 + v;
        int n = n0 + wn * 64 + nf * 16 + (lane & 15);
        float val = acc[mf][nf][v] + bias[n];
        if (C) C[(size_t)m * ldc + n] = val;
        if (C16) C16[(size_t)m * ldc + n] = __float2half(val);
      }
}

// ---------------- GRU: 32 chunk-groups x 8 WGs (1 block/CU), warmup-chunked ----------------
// __launch_bounds__(512, 2): min 2 waves/EU = 1 block/CU -> VGPR cap 256 (wreg 192 + acc 48 fits;
// r12's (512) default capped at 128 and spilled wreg to scratch: WRITE_SIZE 20->72MB).
__global__ __launch_bounds__(512, 2) void gru_kernel(const float* __restrict__ gx,   // [B][L][1536]
                                                     const float* __restrict__ w_hh, // [1536][512]
                                                     const float* __restrict__ b_hh, // [1536]
                                                     __half* __restrict__ statesH,   // [B][L][512] f16
                                                     unsigned long long* __restrict__ bcast) { // [NGRP][2][512]
  const int tid = threadIdx.x;
  const int blk = blockIdx.x;
  const int g = blk >> 3;              // chunk-group 0..31
  const int w = blk & 7;               // worker rank within group
  const int c0 = g * CHUNK;
  const int t0 = (c0 >= WARM) ? (c0 - WARM) : 0;
  const int t_end = c0 + CHUNK;
  const int nsteps = t_end - t0;
  unsigned long long* bc = bcast + (size_t)g * 2 * 512;

  __shared__ __align__(16) __half h16[2][512];
  __shared__ __align__(16) float ghp[4][2][192];          // [k-wave][batch][row]
  __shared__ __align__(16) float gxring[RING][2][3][64];  // [slot][batch][gate][unit]
  const int lane = tid & 63;
  const int wave = tid >> 6;
  const int fr = lane & 15, fkg = lane >> 4;

  // ---- waves 0-3: stage weight K-slice into registers (12 tiles x 16 rows) ----
  f16x8 wreg[12][4];
  if (wave < 4) {
#pragma unroll
    for (int tile = 0; tile < 12; ++tile) {
      int r = tile * 16 + fr;          // 0..191
      int gg = r >> 6, kl = r & 63;
      const float* wrow = w_hh + (size_t)(gg * 512 + w * 64 + kl) * 512 + wave * 128;
#pragma unroll
      for (int j = 0; j < 4; ++j) {
        const float* p = wrow + j * 32 + fkg * 8;
        float4 x = *(const float4*)p;
        float4 y = *(const float4*)(p + 4);
        f16x8 v;
        v[0] = (_Float16)x.x; v[1] = (_Float16)x.y; v[2] = (_Float16)x.z; v[3] = (_Float16)x.w;
        v[4] = (_Float16)y.x; v[5] = (_Float16)y.y; v[6] = (_Float16)y.z; v[7] = (_Float16)y.w;
        wreg[tile][j] = v;
      }
    }
  }
  for (int i = tid; i < 1024; i += 512) h16[i >> 9][i & 511] = __float2half(0.f);

  // ---- ring prologue: slots 0..PF-1 = gx[t0 .. t0+PF) ----
  for (int i = tid; i < PF * 384; i += 512) {
    int s = i / 384, r = i % 384;
    int pb = r / 192, rem = r % 192;
    int pg = rem >> 6, pu = rem & 63;
    gxring[s][pb][pg][pu] = gx[((size_t)pb * L_SZ + (t0 + s)) * 1536 + pg * 512 + w * 64 + pu];
  }

  // ---- wave 4: prefetch registers = gx[t0+PF], both batches ----
  float Rr0 = 0.f, Rz0 = 0.f, Rn0 = 0.f, Rr1 = 0.f, Rz1 = 0.f, Rn1 = 0.f;
  if (wave == 4) {
    const float* gp0 = gx + ((size_t)0 * L_SZ + (t0 + PF)) * 1536 + w * 64 + lane;
    const float* gp1 = gx + ((size_t)1 * L_SZ + (t0 + PF)) * 1536 + w * 64 + lane;
    Rr0 = gp0[0]; Rz0 = gp0[512]; Rn0 = gp0[1024];
    Rr1 = gp1[0]; Rz1 = gp1[512]; Rn1 = gp1[1024];
  }

  // ---- wave 7: gate setup (lane = unit, handles both batches) ----
  const int kglob = w * 64 + lane;
  float bhr = 0.f, bhz = 0.f, bhn = 0.f, hp0 = 0.f, hp1 = 0.f;
  if (wave == 7) { bhr = b_hh[kglob]; bhz = b_hh[512 + kglob]; bhn = b_hh[1024 + kglob]; }

  // ---- waves 5-6: spinner word mapping (448 words, 3.5 per thread) ----
  const int sidx = tid - 320;          // 0..127
  int r0s = 0, j0s = 0, r1s = 0, j1s = 0, r2s = 0, j2s = 0, r3s = 0, j3s = 0;
  bool has3 = false;
  if (wave >= 5 && wave < 7) {
    int i0 = sidx, i1 = sidx + 128, i2 = sidx + 256, i3 = sidx + 384;
    r0s = i0 >> 6; r0s += (r0s >= w); j0s = i0 & 63;
    r1s = i1 >> 6; r1s += (r1s >= w); j1s = i1 & 63;
    r2s = i2 >> 6; r2s += (r2s >= w); j2s = i2 & 63;
    has3 = (sidx < 64);
    if (has3) { r3s = i3 >> 6; r3s += (r3s >= w); j3s = i3 & 63; }
    else { r3s = r0s; j3s = j0s; }     // duplicate word 0 (matches together)
  }
  __syncthreads();

  for (int ts = 0; ts < nsteps; ++ts) {
    const int t = t0 + ts;
    __half hsave0 = __float2half(0.f), hsave1 = __float2half(0.f);
    // ---- phase 1 ----
    if (wave < 4) {
      f32x4 acc[12];
#pragma unroll
      for (int tile = 0; tile < 12; ++tile) acc[tile] = (f32x4){0.f, 0.f, 0.f, 0.f};
#pragma unroll
      for (int j = 0; j < 4; ++j) {
        int kt = wave * 4 + j;
        f16x8 bf = *(const f16x8*)&h16[fr & 1][kt * 32 + fkg * 8];
#pragma unroll
        for (int tile = 0; tile < 12; ++tile)
          acc[tile] = __builtin_amdgcn_mfma_f32_16x16x32_f16(wreg[tile][j], bf, acc[tile], 0, 0, 0);
      }
      if (fr < 2) {
#pragma unroll
        for (int tile = 0; tile < 12; ++tile)
          *(f32x4*)&ghp[wave][fr][tile * 16 + fkg * 4] = acc[tile];
      }
    } else if (wave == 4) {
      hsave0 = h16[0][w * 64 + lane];   // h_{t-1}, stable until phase 2
      hsave1 = h16[1][w * 64 + lane];
    }
    __syncthreads();  // sync1: ghp ready; h16 reads done

    // ---- phase 2 ----
    if (wave == 7) {
      int slot = ts & (RING - 1);
      float gxr0 = gxring[slot][0][0][lane], gxz0 = gxring[slot][0][1][lane], gxn0 = gxring[slot][0][2][lane];
      float gxr1 = gxring[slot][1][0][lane], gxz1 = gxring[slot][1][1][lane], gxn1 = gxring[slot][1][2][lane];
      float ghr0 = ghp[0][0][lane] + ghp[1][0][lane] + ghp[2][0][lane] + ghp[3][0][lane];
      float ghz0 = ghp[0][0][64 + lane] + ghp[1][0][64 + lane] + ghp[2][0][64 + lane] + ghp[3][0][64 + lane];
      float ghn0 = ghp[0][0][128 + lane] + ghp[1][0][128 + lane] + ghp[2][0][128 + lane] + ghp[3][0][128 + lane];
      float ghr1 = ghp[0][1][lane] + ghp[1][1][lane] + ghp[2][1][lane] + ghp[3][1][lane];
      float ghz1 = ghp[0][1][64 + lane] + ghp[1][1][64 + lane] + ghp[2][1][64 + lane] + ghp[3][1][64 + lane];
      float ghn1 = ghp[0][1][128 + lane] + ghp[1][1][128 + lane] + ghp[2][1][128 + lane] + ghp[3][1][128 + lane];
      float rr0 = 1.f / (1.f + __expf(-(gxr0 + ghr0 + bhr)));
      float rr1 = 1.f / (1.f + __expf(-(gxr1 + ghr1 + bhr)));
      float zz0 = 1.f / (1.f + __expf(-(gxz0 + ghz0 + bhz)));
      float zz1 = 1.f / (1.f + __expf(-(gxz1 + ghz1 + bhz)));
      float y0 = gxn0 + rr0 * (ghn0 + bhn);
      float y1 = gxn1 + rr1 * (ghn1 + bhn);
      float e20 = __expf(2.f * y0), e21 = __expf(2.f * y1);
      float nn0 = 1.f - 2.f / (e20 + 1.f);
      float nn1 = 1.f - 2.f / (e21 + 1.f);
      float hv0 = (1.f - zz0) * nn0 + zz0 * hp0;
      float hv1 = (1.f - zz1) * nn1 + zz1 * hp1;
      hp0 = hv0; hp1 = hv1;
      __half h0 = __float2half(hv0), h1 = __float2half(hv1);
      h16[0][kglob] = h0;
      h16[1][kglob] = h1;
      unsigned long long pk = ((unsigned long long)(unsigned)(ts + 1) << 32)
                            | (unsigned long long)__half_as_ushort(h0)
                            | ((unsigned long long)__half_as_ushort(h1) << 16);
      __hip_atomic_store(&bc[(size_t)(ts & 1) * 512 + kglob], pk,
                         __ATOMIC_RELAXED, __HIP_MEMORY_SCOPE_AGENT);
    } else if (wave == 4) {
      if (t > c0) {
        statesH[((size_t)0 * L_SZ + (t - 1)) * 512 + w * 64 + lane] = hsave0;
        statesH[((size_t)1 * L_SZ + (t - 1)) * 512 + w * 64 + lane] = hsave1;
      }
      int slot = (ts + PF) & (RING - 1);
      gxring[slot][0][0][lane] = Rr0; gxring[slot][0][1][lane] = Rz0; gxring[slot][0][2][lane] = Rn0;
      gxring[slot][1][0][lane] = Rr1; gxring[slot][1][1][lane] = Rz1; gxring[slot][1][2][lane] = Rn1;
      int tg = t0 + ts + PF + 1; if (tg > t_end - 1) tg = t_end - 1;
      const float* gp0 = gx + ((size_t)0 * L_SZ + tg) * 1536 + w * 64 + lane;
      const float* gp1 = gx + ((size_t)1 * L_SZ + tg) * 1536 + w * 64 + lane;
      Rr0 = gp0[0]; Rz0 = gp0[512]; Rn0 = gp0[1024];
      Rr1 = gp1[0]; Rz1 = gp1[512]; Rn1 = gp1[1024];
    } else if (wave >= 5) {
      const unsigned want = (unsigned)(ts + 1);
      const unsigned long long* base = bc + (size_t)(ts & 1) * 512;
      const unsigned long long* a0 = base + r0s * 64 + j0s;
      const unsigned long long* a1 = base + r1s * 64 + j1s;
      const unsigned long long* a2 = base + r2s * 64 + j2s;
      const unsigned long long* a3 = base + r3s * 64 + j3s;
      unsigned long long v0, v1, v2, v3;
      do {
        v0 = __hip_atomic_load(a0, __ATOMIC_RELAXED, __HIP_MEMORY_SCOPE_AGENT);
        v1 = __hip_atomic_load(a1, __ATOMIC_RELAXED, __HIP_MEMORY_SCOPE_AGENT);
        v2 = __hip_atomic_load(a2, __ATOMIC_RELAXED, __HIP_MEMORY_SCOPE_AGENT);
        v3 = has3 ? __hip_atomic_load(a3, __ATOMIC_RELAXED, __HIP_MEMORY_SCOPE_AGENT)
                  : ((unsigned long long)want << 32);
      } while ((unsigned)(v0 >> 32) != want || (unsigned)(v1 >> 32) != want ||
               (unsigned)(v2 >> 32) != want || (unsigned)(v3 >> 32) != want);
      h16[0][r0s * 64 + j0s] = __ushort_as_half((unsigned short)v0);
      h16[1][r0s * 64 + j0s] = __ushort_as_half((unsigned short)(v0 >> 16));
      h16[0][r1s * 64 + j1s] = __ushort_as_half((unsigned short)v1);
      h16[1][r1s * 64 + j1s] = __ushort_as_half((unsigned short)(v1 >> 16));
      h16[0][r2s * 64 + j2s] = __ushort_as_half((unsigned short)v2);
      h16[1][r2s * 64 + j2s] = __ushort_as_half((unsigned short)(v2 >> 16));
      if (has3) {
        h16[0][r3s * 64 + j3s] = __ushort_as_half((unsigned short)v3);
        h16[1][r3s * 64 + j3s] = __ushort_as_half((unsigned short)(v3 >> 16));
      }
    }
    __syncthreads();  // sync2: h16 complete for next step
  }
  if (wave == 4) {  // final state of this chunk
    statesH[((size_t)0 * L_SZ + (t_end - 1)) * 512 + w * 64 + lane] = h16[0][w * 64 + lane];
    statesH[((size_t)1 * L_SZ + (t_end - 1)) * 512 + w * 64 + lane] = h16[1][w * 64 + lane];
  }
}

// ---------------- windowed attention + scatter-add, gate computed inline ----------------
// q = qk[:, 0:128], k = qk[:, 128:256] with row stride 512
__global__ __launch_bounds__(128) void attn_kernel(const float* __restrict__ qk,
                                                   const __half* __restrict__ states,
                                                   const float* __restrict__ wg,
                                                   const float* __restrict__ bg,
                                                   const int* __restrict__ ids,
                                                   const float* __restrict__ mem_scale,
                                                   float* __restrict__ out) {
  __shared__ float qs[128];
  __shared__ float cm[2], cs[2], cg[2];
  const int bi = blockIdx.x;
  const int i = bi & (L_SZ - 1), b = bi >> 11;
  if (i == 0) return;
  const int w0 = (i > 128) ? (i - 128) : 0;
  const int wlen = i - w0;
  const int tid = threadIdx.x;
  const int ln = tid & 63, wv = tid >> 6;
  qs[tid] = qk[(size_t)bi * 512 + tid];
  // inline gate partial: dot(states[bi], wg), 4 elems/thread
  uint2 hv = *(const uint2*)&states[(size_t)bi * 512 + tid * 4];
  float2 f01 = __half22float2(*(__half2*)&hv.x);
  float2 f23 = __half22float2(*(__half2*)&hv.y);
  float gpart = f01.x * wg[tid * 4] + f01.y * wg[tid * 4 + 1] +
                f23.x * wg[tid * 4 + 2] + f23.y * wg[tid * 4 + 3];
#pragma unroll
  for (int off = 32; off; off >>= 1) gpart += __shfl_xor(gpart, off);
  if (ln == 0) cg[wv] = gpart;
  __syncthreads();
  float s = -1e30f;
  if (tid < wlen) {
    const float4* kr = (const float4*)&qk[(size_t)(b * L_SZ + w0 + tid) * 512 + 128];
    const float4* qr = (const float4*)qs;
    float a0 = 0.f, a1 = 0.f, a2 = 0.f, a3 = 0.f;
#pragma unroll 8
    for (int c = 0; c < 32; ++c) {
      float4 kv = kr[c];
      float4 qv = qr[c];
      a0 = fmaf(kv.x, qv.x, a0); a1 = fmaf(kv.y, qv.y, a1);
      a2 = fmaf(kv.z, qv.z, a2); a3 = fmaf(kv.w, qv.w, a3);
    }
    s = ((a0 + a1) + (a2 + a3)) * 0.08838834764831845f;  // 1/sqrt(128)
  }
  float m = s;
#pragma unroll
  for (int off = 32; off; off >>= 1) m = fmaxf(m, __shfl_xor(m, off));
  if (ln == 0) cm[wv] = m;
  __syncthreads();
  float mx = fmaxf(cm[0], cm[1]);
  float p = (tid < wlen) ? __expf(s - mx) : 0.f;
  float sum = p;
#pragma unroll
  for (int off = 32; off; off >>= 1) sum += __shfl_xor(sum, off);
  if (ln == 0) cs[wv] = sum;
  __syncthreads();
  float gateval = 1.f / (1.f + __expf(-(cg[0] + cg[1] + bg[0])));
  float inv = 1.f / (cs[0] + cs[1]);
  if (tid < wlen) {
    float val = p * inv * gateval * mem_scale[0];
    int id = ids[b * L_SZ + w0 + tid];
    atomicAdd(&out[(size_t)bi * VCAB + id], val);
  }
}

// ---------------- launch ----------------
extern "C" void kernel_launch(void* const* d_in, const int* in_sizes, int n_in,
                              void* d_out, int out_size, void* d_ws, size_t ws_size,
                              hipStream_t stream) {
  (void)in_sizes; (void)n_in; (void)out_size; (void)ws_size;
  const int* ids = (const int*)d_in[0];
  const float* emb = (const float*)d_in[1];
  const float* w_ih = (const float*)d_in[2];
  const float* w_hh = (const float*)d_in[3];
  const float* b_ih = (const float*)d_in[4];
  const float* b_hh = (const float*)d_in[5];
  const float* wq = (const float*)d_in[6];
  const float* bq = (const float*)d_in[7];
  const float* wk = (const float*)d_in[8];
  const float* bk = (const float*)d_in[9];
  const float* wg = (const float*)d_in[10];
  const float* bg = (const float*)d_in[11];
  const float* wh = (const float*)d_in[12];
  const float* bh = (const float*)d_in[13];
  const float* outb = (const float*)d_in[14];
  const float* memsc = (const float*)d_in[15];
  float* out = (float*)d_out;

  char* ws = (char*)d_ws;
  size_t off = 0;
  auto alloc = [&](size_t bytes) {
    void* p = ws + off;
    off = (off + bytes + 255) & ~(size_t)255;
    return p;
  };
  unsigned long long* bcast = (unsigned long long*)alloc((size_t)NGRP * 2 * 512 * 8);
  float* gx = (float*)alloc((size_t)4096 * 1536 * 4);
  float* biascat = (float*)alloc(512 * 4);
  float* qkcat = (float*)alloc((size_t)4096 * 512 * 4);
  __half* embH = (__half*)alloc((size_t)VCAB * 256 * 2);
  __half* w_ihH = (__half*)alloc((size_t)1536 * 256 * 2);
  __half* statesH = (__half*)alloc((size_t)4096 * 512 * 2);
  __half* WcatH = (__half*)alloc((size_t)512 * 512 * 2);
  __half* qkcatH = (__half*)alloc((size_t)4096 * 512 * 2);

  hipMemsetAsync(bcast, 0, (size_t)NGRP * 2 * 512 * 8, stream);
  conv_f16_kernel<<<(VCAB * 256 / 4 + 255) / 256, 256, 0, stream>>>(emb, embH, VCAB * 256 / 4);
  conv_f16_kernel<<<(1536 * 256 / 4 + 255) / 256, 256, 0, stream>>>(w_ih, w_ihH, 1536 * 256 / 4);
  prep_kernel<<<256, 256, 0, stream>>>(wq, wk, wh, bq, bk, bh, WcatH, biascat);
  // gx = emb[ids] @ w_ih^T + b_ih
  mfma_gemm_kernel<<<dim3(1536 / 128, 4096 / 128), 256, 0, stream>>>(
      embH, w_ihH, b_ih, gx, nullptr, 4096, 1536, 256, 256, 1536, ids);
  gru_kernel<<<NGRP * GRU_WGS, 512, 0, stream>>>(gx, w_hh, b_hh, statesH, bcast);
  // fused q|k|h_emb projection: qkcat f32 (q,k) + qkcatH f16 (h_emb for base GEMM)
  mfma_gemm_kernel<<<dim3(512 / 128, 4096 / 128), 256, 0, stream>>>(
      statesH, WcatH, biascat, qkcat, qkcatH, 4096, 512, 512, 512, 512, nullptr);
  // base logits: A = h_emb slice of qkcatH (cols 256..511, row stride 512)
  mfma_gemm_kernel<<<dim3(VCAB / 128, 4096 / 128), 256, 0, stream>>>(
      qkcatH + 256, embH, outb, out, nullptr, 4096, VCAB, 256, 512, VCAB, nullptr);
  attn_kernel<<<4096, 128, 0, stream>>>(qkcat, statesH, wg, bg, ids, memsc, out);
}

// Round 14
// 809.226 us; speedup vs baseline: 1.0024x; 1.0024x over previous
//
#include <hip/hip_runtime.h>
#include <hip/hip_fp16.h>

#define L_SZ 2048
#define VCAB 32000
#define GRU_WGS 8
#define NGRP 32
#define CHUNK 64
#define WARM 128
#define PF 12
#define RING 16

typedef __attribute__((ext_vector_type(8))) _Float16 f16x8;
typedef __attribute__((ext_vector_type(4))) float f32x4;

// ---------------- f32 -> f16 conversion (4 elems/thread) ----------------
__global__ __launch_bounds__(256) void conv_f16_kernel(const float* __restrict__ in,
                                                       __half* __restrict__ out, int n4) {
  int i = blockIdx.x * 256 + threadIdx.x;
  if (i >= n4) return;
  float4 v = ((const float4*)in)[i];
  __half2 a = __floats2half2_rn(v.x, v.y);
  __half2 b = __floats2half2_rn(v.z, v.w);
  uint2 u;
  u.x = *(unsigned*)&a;
  u.y = *(unsigned*)&b;
  ((uint2*)out)[i] = u;
}

// ---------------- prep: Wcat=[wq;wk;wh] f16 + biascat=[bq;bk;bh] f32, one launch ----------------
__global__ __launch_bounds__(256) void prep_kernel(const float* __restrict__ wq,
                                                   const float* __restrict__ wk,
                                                   const float* __restrict__ wh,
                                                   const float* __restrict__ bq,
                                                   const float* __restrict__ bk,
                                                   const float* __restrict__ bh,
                                                   __half* __restrict__ Wcat,
                                                   float* __restrict__ biascat) {
  int idx = blockIdx.x * 256 + threadIdx.x;   // 0..65535 (512*512/4)
  int e = idx * 4;
  int row = e >> 9, col = e & 511;
  const float* src = (row < 128) ? &wq[row * 512 + col]
                   : (row < 256) ? &wk[(row - 128) * 512 + col]
                                 : &wh[(row - 256) * 512 + col];
  float4 v = *(const float4*)src;
  __half2 a = __floats2half2_rn(v.x, v.y);
  __half2 b = __floats2half2_rn(v.z, v.w);
  uint2 u;
  u.x = *(unsigned*)&a;
  u.y = *(unsigned*)&b;
  ((uint2*)Wcat)[idx] = u;
  if (idx < 512)
    biascat[idx] = (idx < 128) ? bq[idx] : (idx < 256) ? bk[idx - 128] : bh[idx - 256];
}

// ---------------- generic MFMA GEMM, global_load_lds staging, XCD-swizzled ----------------
// C[m][n] = bias[n] + A_f16[row(m)] . W_f16[n]; A row stride lda; W row stride K.
__global__ __launch_bounds__(256) void mfma_gemm_kernel(const __half* __restrict__ A,
                                                        const __half* __restrict__ W,
                                                        const float* __restrict__ bias,
                                                        float* __restrict__ C,
                                                        __half* __restrict__ C16,
                                                        int M, int N, int K, int lda, int ldc,
                                                        const int* __restrict__ gather) {
  __shared__ __align__(16) __half Al[128 * 32];
  __shared__ __align__(16) __half Wl[128 * 32];
  const int tid = threadIdx.x;
  const int nbx = gridDim.x;
  int flat = blockIdx.y * nbx + blockIdx.x;
  int cpx = (nbx * gridDim.y) >> 3;
  int swz = (flat & 7) * cpx + (flat >> 3);
  const int n0 = (swz % nbx) * 128, m0 = (swz / nbx) * 128;
  const int lane = tid & 63, wave = tid >> 6;
  const int wm = wave >> 1, wn = wave & 1;
  const int fr = lane & 15, fk = (lane >> 4) * 8;
  const int r0 = tid >> 2, q0 = tid & 3;
  const int r1 = (tid + 256) >> 2, q1 = tid & 3;
  const int arow0 = gather ? gather[m0 + r0] : (m0 + r0);
  const int arow1 = gather ? gather[m0 + r1] : (m0 + r1);
  __half* a0d = &Al[wave * 512];
  __half* a1d = &Al[wave * 512 + 2048];
  __half* w0d = &Wl[wave * 512];
  __half* w1d = &Wl[wave * 512 + 2048];

  f32x4 acc[4][4];
#pragma unroll
  for (int i = 0; i < 4; ++i)
#pragma unroll
    for (int j = 0; j < 4; ++j) acc[i][j] = (f32x4){0.f, 0.f, 0.f, 0.f};

  for (int kt = 0; kt < K; kt += 32) {
    __builtin_amdgcn_global_load_lds((const unsigned int*)(A + (size_t)arow0 * lda + kt + q0 * 8),
                                     (unsigned int*)a0d, 16, 0, 0);
    __builtin_amdgcn_global_load_lds((const unsigned int*)(A + (size_t)arow1 * lda + kt + q1 * 8),
                                     (unsigned int*)a1d, 16, 0, 0);
    __builtin_amdgcn_global_load_lds((const unsigned int*)(W + (size_t)(n0 + r0) * K + kt + q0 * 8),
                                     (unsigned int*)w0d, 16, 0, 0);
    __builtin_amdgcn_global_load_lds((const unsigned int*)(W + (size_t)(n0 + r1) * K + kt + q1 * 8),
                                     (unsigned int*)w1d, 16, 0, 0);
    __syncthreads();
    f16x8 af[4], bfv[4];
#pragma unroll
    for (int mf = 0; mf < 4; ++mf) af[mf] = *(const f16x8*)&Al[(wm * 64 + mf * 16 + fr) * 32 + fk];
#pragma unroll
    for (int nf = 0; nf < 4; ++nf) bfv[nf] = *(const f16x8*)&Wl[(wn * 64 + nf * 16 + fr) * 32 + fk];
#pragma unroll
    for (int mf = 0; mf < 4; ++mf)
#pragma unroll
      for (int nf = 0; nf < 4; ++nf)
        acc[mf][nf] = __builtin_amdgcn_mfma_f32_16x16x32_f16(af[mf], bfv[nf], acc[mf][nf], 0, 0, 0);
    __syncthreads();
  }
  const int r4 = (lane >> 4) * 4;
#pragma unroll
  for (int mf = 0; mf < 4; ++mf)
#pragma unroll
    for (int nf = 0; nf < 4; ++nf)
#pragma unroll
      for (int v = 0; v < 4; ++v) {
        int m = m0 + wm * 64 + mf * 16 + r4 + v;
        int n = n0 + wn * 64 + nf * 16 + (lane & 15);
        float val = acc[mf][nf][v] + bias[n];
        if (C) C[(size_t)m * ldc + n] = val;
        if (C16) C16[(size_t)m * ldc + n] = __float2half(val);
      }
}

// ---------------- GRU: 32 chunk-groups x 8 WGs (1 block/CU), warmup-chunked ----------------
// __launch_bounds__(512, 1): r13's (512,2) still capped VGPR at 128 (toolchain treats arg 2
// CUDA-style as blocks/CU: 2 blocks -> 4 waves/EU -> 128). With 1: either semantics gives
// cap >= 256, fitting wreg 192 + acc 48 without scratch spill.
__global__ __launch_bounds__(512, 1) void gru_kernel(const float* __restrict__ gx,   // [B][L][1536]
                                                     const float* __restrict__ w_hh, // [1536][512]
                                                     const float* __restrict__ b_hh, // [1536]
                                                     __half* __restrict__ statesH,   // [B][L][512] f16
                                                     unsigned long long* __restrict__ bcast) { // [NGRP][2][512]
  const int tid = threadIdx.x;
  const int blk = blockIdx.x;
  const int g = blk >> 3;              // chunk-group 0..31
  const int w = blk & 7;               // worker rank within group
  const int c0 = g * CHUNK;
  const int t0 = (c0 >= WARM) ? (c0 - WARM) : 0;
  const int t_end = c0 + CHUNK;
  const int nsteps = t_end - t0;
  unsigned long long* bc = bcast + (size_t)g * 2 * 512;

  __shared__ __align__(16) __half h16[2][512];
  __shared__ __align__(16) float ghp[4][2][192];          // [k-wave][batch][row]
  __shared__ __align__(16) float gxring[RING][2][3][64];  // [slot][batch][gate][unit]
  const int lane = tid & 63;
  const int wave = tid >> 6;
  const int fr = lane & 15, fkg = lane >> 4;

  // ---- waves 0-3: stage weight K-slice into registers (12 tiles x 16 rows) ----
  f16x8 wreg[12][4];
  if (wave < 4) {
#pragma unroll
    for (int tile = 0; tile < 12; ++tile) {
      int r = tile * 16 + fr;          // 0..191
      int gg = r >> 6, kl = r & 63;
      const float* wrow = w_hh + (size_t)(gg * 512 + w * 64 + kl) * 512 + wave * 128;
#pragma unroll
      for (int j = 0; j < 4; ++j) {
        const float* p = wrow + j * 32 + fkg * 8;
        float4 x = *(const float4*)p;
        float4 y = *(const float4*)(p + 4);
        f16x8 v;
        v[0] = (_Float16)x.x; v[1] = (_Float16)x.y; v[2] = (_Float16)x.z; v[3] = (_Float16)x.w;
        v[4] = (_Float16)y.x; v[5] = (_Float16)y.y; v[6] = (_Float16)y.z; v[7] = (_Float16)y.w;
        wreg[tile][j] = v;
      }
    }
  }
  for (int i = tid; i < 1024; i += 512) h16[i >> 9][i & 511] = __float2half(0.f);

  // ---- ring prologue: slots 0..PF-1 = gx[t0 .. t0+PF) ----
  for (int i = tid; i < PF * 384; i += 512) {
    int s = i / 384, r = i % 384;
    int pb = r / 192, rem = r % 192;
    int pg = rem >> 6, pu = rem & 63;
    gxring[s][pb][pg][pu] = gx[((size_t)pb * L_SZ + (t0 + s)) * 1536 + pg * 512 + w * 64 + pu];
  }

  // ---- wave 4: prefetch registers = gx[t0+PF], both batches ----
  float Rr0 = 0.f, Rz0 = 0.f, Rn0 = 0.f, Rr1 = 0.f, Rz1 = 0.f, Rn1 = 0.f;
  if (wave == 4) {
    const float* gp0 = gx + ((size_t)0 * L_SZ + (t0 + PF)) * 1536 + w * 64 + lane;
    const float* gp1 = gx + ((size_t)1 * L_SZ + (t0 + PF)) * 1536 + w * 64 + lane;
    Rr0 = gp0[0]; Rz0 = gp0[512]; Rn0 = gp0[1024];
    Rr1 = gp1[0]; Rz1 = gp1[512]; Rn1 = gp1[1024];
  }

  // ---- wave 7: gate setup (lane = unit, handles both batches) ----
  const int kglob = w * 64 + lane;
  float bhr = 0.f, bhz = 0.f, bhn = 0.f, hp0 = 0.f, hp1 = 0.f;
  if (wave == 7) { bhr = b_hh[kglob]; bhz = b_hh[512 + kglob]; bhn = b_hh[1024 + kglob]; }

  // ---- waves 5-6: spinner word mapping (448 words, 3.5 per thread) ----
  const int sidx = tid - 320;          // 0..127
  int r0s = 0, j0s = 0, r1s = 0, j1s = 0, r2s = 0, j2s = 0, r3s = 0, j3s = 0;
  bool has3 = false;
  if (wave >= 5 && wave < 7) {
    int i0 = sidx, i1 = sidx + 128, i2 = sidx + 256, i3 = sidx + 384;
    r0s = i0 >> 6; r0s += (r0s >= w); j0s = i0 & 63;
    r1s = i1 >> 6; r1s += (r1s >= w); j1s = i1 & 63;
    r2s = i2 >> 6; r2s += (r2s >= w); j2s = i2 & 63;
    has3 = (sidx < 64);
    if (has3) { r3s = i3 >> 6; r3s += (r3s >= w); j3s = i3 & 63; }
    else { r3s = r0s; j3s = j0s; }     // duplicate word 0 (matches together)
  }
  __syncthreads();

  for (int ts = 0; ts < nsteps; ++ts) {
    const int t = t0 + ts;
    __half hsave0 = __float2half(0.f), hsave1 = __float2half(0.f);
    // ---- phase 1 ----
    if (wave < 4) {
      f32x4 acc[12];
#pragma unroll
      for (int tile = 0; tile < 12; ++tile) acc[tile] = (f32x4){0.f, 0.f, 0.f, 0.f};
#pragma unroll
      for (int j = 0; j < 4; ++j) {
        int kt = wave * 4 + j;
        f16x8 bf = *(const f16x8*)&h16[fr & 1][kt * 32 + fkg * 8];
#pragma unroll
        for (int tile = 0; tile < 12; ++tile)
          acc[tile] = __builtin_amdgcn_mfma_f32_16x16x32_f16(wreg[tile][j], bf, acc[tile], 0, 0, 0);
      }
      if (fr < 2) {
#pragma unroll
        for (int tile = 0; tile < 12; ++tile)
          *(f32x4*)&ghp[wave][fr][tile * 16 + fkg * 4] = acc[tile];
      }
    } else if (wave == 4) {
      hsave0 = h16[0][w * 64 + lane];   // h_{t-1}, stable until phase 2
      hsave1 = h16[1][w * 64 + lane];
    }
    __syncthreads();  // sync1: ghp ready; h16 reads done

    // ---- phase 2 ----
    if (wave == 7) {
      int slot = ts & (RING - 1);
      float gxr0 = gxring[slot][0][0][lane], gxz0 = gxring[slot][0][1][lane], gxn0 = gxring[slot][0][2][lane];
      float gxr1 = gxring[slot][1][0][lane], gxz1 = gxring[slot][1][1][lane], gxn1 = gxring[slot][1][2][lane];
      float ghr0 = ghp[0][0][lane] + ghp[1][0][lane] + ghp[2][0][lane] + ghp[3][0][lane];
      float ghz0 = ghp[0][0][64 + lane] + ghp[1][0][64 + lane] + ghp[2][0][64 + lane] + ghp[3][0][64 + lane];
      float ghn0 = ghp[0][0][128 + lane] + ghp[1][0][128 + lane] + ghp[2][0][128 + lane] + ghp[3][0][128 + lane];
      float ghr1 = ghp[0][1][lane] + ghp[1][1][lane] + ghp[2][1][lane] + ghp[3][1][lane];
      float ghz1 = ghp[0][1][64 + lane] + ghp[1][1][64 + lane] + ghp[2][1][64 + lane] + ghp[3][1][64 + lane];
      float ghn1 = ghp[0][1][128 + lane] + ghp[1][1][128 + lane] + ghp[2][1][128 + lane] + ghp[3][1][128 + lane];
      float rr0 = 1.f / (1.f + __expf(-(gxr0 + ghr0 + bhr)));
      float rr1 = 1.f / (1.f + __expf(-(gxr1 + ghr1 + bhr)));
      float zz0 = 1.f / (1.f + __expf(-(gxz0 + ghz0 + bhz)));
      float zz1 = 1.f / (1.f + __expf(-(gxz1 + ghz1 + bhz)));
      float y0 = gxn0 + rr0 * (ghn0 + bhn);
      float y1 = gxn1 + rr1 * (ghn1 + bhn);
      float e20 = __expf(2.f * y0), e21 = __expf(2.f * y1);
      float nn0 = 1.f - 2.f / (e20 + 1.f);
      float nn1 = 1.f - 2.f / (e21 + 1.f);
      float hv0 = (1.f - zz0) * nn0 + zz0 * hp0;
      float hv1 = (1.f - zz1) * nn1 + zz1 * hp1;
      hp0 = hv0; hp1 = hv1;
      __half h0 = __float2half(hv0), h1 = __float2half(hv1);
      h16[0][kglob] = h0;
      h16[1][kglob] = h1;
      unsigned long long pk = ((unsigned long long)(unsigned)(ts + 1) << 32)
                            | (unsigned long long)__half_as_ushort(h0)
                            | ((unsigned long long)__half_as_ushort(h1) << 16);
      __hip_atomic_store(&bc[(size_t)(ts & 1) * 512 + kglob], pk,
                         __ATOMIC_RELAXED, __HIP_MEMORY_SCOPE_AGENT);
    } else if (wave == 4) {
      if (t > c0) {
        statesH[((size_t)0 * L_SZ + (t - 1)) * 512 + w * 64 + lane] = hsave0;
        statesH[((size_t)1 * L_SZ + (t - 1)) * 512 + w * 64 + lane] = hsave1;
      }
      int slot = (ts + PF) & (RING - 1);
      gxring[slot][0][0][lane] = Rr0; gxring[slot][0][1][lane] = Rz0; gxring[slot][0][2][lane] = Rn0;
      gxring[slot][1][0][lane] = Rr1; gxring[slot][1][1][lane] = Rz1; gxring[slot][1][2][lane] = Rn1;
      int tg = t0 + ts + PF + 1; if (tg > t_end - 1) tg = t_end - 1;
      const float* gp0 = gx + ((size_t)0 * L_SZ + tg) * 1536 + w * 64 + lane;
      const float* gp1 = gx + ((size_t)1 * L_SZ + tg) * 1536 + w * 64 + lane;
      Rr0 = gp0[0]; Rz0 = gp0[512]; Rn0 = gp0[1024];
      Rr1 = gp1[0]; Rz1 = gp1[512]; Rn1 = gp1[1024];
    } else if (wave >= 5) {
      const unsigned want = (unsigned)(ts + 1);
      const unsigned long long* base = bc + (size_t)(ts & 1) * 512;
      const unsigned long long* a0 = base + r0s * 64 + j0s;
      const unsigned long long* a1 = base + r1s * 64 + j1s;
      const unsigned long long* a2 = base + r2s * 64 + j2s;
      const unsigned long long* a3 = base + r3s * 64 + j3s;
      unsigned long long v0, v1, v2, v3;
      do {
        v0 = __hip_atomic_load(a0, __ATOMIC_RELAXED, __HIP_MEMORY_SCOPE_AGENT);
        v1 = __hip_atomic_load(a1, __ATOMIC_RELAXED, __HIP_MEMORY_SCOPE_AGENT);
        v2 = __hip_atomic_load(a2, __ATOMIC_RELAXED, __HIP_MEMORY_SCOPE_AGENT);
        v3 = has3 ? __hip_atomic_load(a3, __ATOMIC_RELAXED, __HIP_MEMORY_SCOPE_AGENT)
                  : ((unsigned long long)want << 32);
      } while ((unsigned)(v0 >> 32) != want || (unsigned)(v1 >> 32) != want ||
               (unsigned)(v2 >> 32) != want || (unsigned)(v3 >> 32) != want);
      h16[0][r0s * 64 + j0s] = __ushort_as_half((unsigned short)v0);
      h16[1][r0s * 64 + j0s] = __ushort_as_half((unsigned short)(v0 >> 16));
      h16[0][r1s * 64 + j1s] = __ushort_as_half((unsigned short)v1);
      h16[1][r1s * 64 + j1s] = __ushort_as_half((unsigned short)(v1 >> 16));
      h16[0][r2s * 64 + j2s] = __ushort_as_half((unsigned short)v2);
      h16[1][r2s * 64 + j2s] = __ushort_as_half((unsigned short)(v2 >> 16));
      if (has3) {
        h16[0][r3s * 64 + j3s] = __ushort_as_half((unsigned short)v3);
        h16[1][r3s * 64 + j3s] = __ushort_as_half((unsigned short)(v3 >> 16));
      }
    }
    __syncthreads();  // sync2: h16 complete for next step
  }
  if (wave == 4) {  // final state of this chunk
    statesH[((size_t)0 * L_SZ + (t_end - 1)) * 512 + w * 64 + lane] = h16[0][w * 64 + lane];
    statesH[((size_t)1 * L_SZ + (t_end - 1)) * 512 + w * 64 + lane] = h16[1][w * 64 + lane];
  }
}

// ---------------- windowed attention + scatter-add, gate computed inline ----------------
// q = qk[:, 0:128], k = qk[:, 128:256] with row stride 512
__global__ __launch_bounds__(128) void attn_kernel(const float* __restrict__ qk,
                                                   const __half* __restrict__ states,
                                                   const float* __restrict__ wg,
                                                   const float* __restrict__ bg,
                                                   const int* __restrict__ ids,
                                                   const float* __restrict__ mem_scale,
                                                   float* __restrict__ out) {
  __shared__ float qs[128];
  __shared__ float cm[2], cs[2], cg[2];
  const int bi = blockIdx.x;
  const int i = bi & (L_SZ - 1), b = bi >> 11;
  if (i == 0) return;
  const int w0 = (i > 128) ? (i - 128) : 0;
  const int wlen = i - w0;
  const int tid = threadIdx.x;
  const int ln = tid & 63, wv = tid >> 6;
  qs[tid] = qk[(size_t)bi * 512 + tid];
  // inline gate partial: dot(states[bi], wg), 4 elems/thread
  uint2 hv = *(const uint2*)&states[(size_t)bi * 512 + tid * 4];
  float2 f01 = __half22float2(*(__half2*)&hv.x);
  float2 f23 = __half22float2(*(__half2*)&hv.y);
  float gpart = f01.x * wg[tid * 4] + f01.y * wg[tid * 4 + 1] +
                f23.x * wg[tid * 4 + 2] + f23.y * wg[tid * 4 + 3];
#pragma unroll
  for (int off = 32; off; off >>= 1) gpart += __shfl_xor(gpart, off);
  if (ln == 0) cg[wv] = gpart;
  __syncthreads();
  float s = -1e30f;
  if (tid < wlen) {
    const float4* kr = (const float4*)&qk[(size_t)(b * L_SZ + w0 + tid) * 512 + 128];
    const float4* qr = (const float4*)qs;
    float a0 = 0.f, a1 = 0.f, a2 = 0.f, a3 = 0.f;
#pragma unroll 8
    for (int c = 0; c < 32; ++c) {
      float4 kv = kr[c];
      float4 qv = qr[c];
      a0 = fmaf(kv.x, qv.x, a0); a1 = fmaf(kv.y, qv.y, a1);
      a2 = fmaf(kv.z, qv.z, a2); a3 = fmaf(kv.w, qv.w, a3);
    }
    s = ((a0 + a1) + (a2 + a3)) * 0.08838834764831845f;  // 1/sqrt(128)
  }
  float m = s;
#pragma unroll
  for (int off = 32; off; off >>= 1) m = fmaxf(m, __shfl_xor(m, off));
  if (ln == 0) cm[wv] = m;
  __syncthreads();
  float mx = fmaxf(cm[0], cm[1]);
  float p = (tid < wlen) ? __expf(s - mx) : 0.f;
  float sum = p;
#pragma unroll
  for (int off = 32; off; off >>= 1) sum += __shfl_xor(sum, off);
  if (ln == 0) cs[wv] = sum;
  __syncthreads();
  float gateval = 1.f / (1.f + __expf(-(cg[0] + cg[1] + bg[0])));
  float inv = 1.f / (cs[0] + cs[1]);
  if (tid < wlen) {
    float val = p * inv * gateval * mem_scale[0];
    int id = ids[b * L_SZ + w0 + tid];
    atomicAdd(&out[(size_t)bi * VCAB + id], val);
  }
}

// ---------------- launch ----------------
extern "C" void kernel_launch(void* const* d_in, const int* in_sizes, int n_in,
                              void* d_out, int out_size, void* d_ws, size_t ws_size,
                              hipStream_t stream) {
  (void)in_sizes; (void)n_in; (void)out_size; (void)ws_size;
  const int* ids = (const int*)d_in[0];
  const float* emb = (const float*)d_in[1];
  const float* w_ih = (const float*)d_in[2];
  const float* w_hh = (const float*)d_in[3];
  const float* b_ih = (const float*)d_in[4];
  const float* b_hh = (const float*)d_in[5];
  const float* wq = (const float*)d_in[6];
  const float* bq = (const float*)d_in[7];
  const float* wk = (const float*)d_in[8];
  const float* bk = (const float*)d_in[9];
  const float* wg = (const float*)d_in[10];
  const float* bg = (const float*)d_in[11];
  const float* wh = (const float*)d_in[12];
  const float* bh = (const float*)d_in[13];
  const float* outb = (const float*)d_in[14];
  const float* memsc = (const float*)d_in[15];
  float* out = (float*)d_out;

  char* ws = (char*)d_ws;
  size_t off = 0;
  auto alloc = [&](size_t bytes) {
    void* p = ws + off;
    off = (off + bytes + 255) & ~(size_t)255;
    return p;
  };
  unsigned long long* bcast = (unsigned long long*)alloc((size_t)NGRP * 2 * 512 * 8);
  float* gx = (float*)alloc((size_t)4096 * 1536 * 4);
  float* biascat = (float*)alloc(512 * 4);
  float* qkcat = (float*)alloc((size_t)4096 * 512 * 4);
  __half* embH = (__half*)alloc((size_t)VCAB * 256 * 2);
  __half* w_ihH = (__half*)alloc((size_t)1536 * 256 * 2);
  __half* statesH = (__half*)alloc((size_t)4096 * 512 * 2);
  __half* WcatH = (__half*)alloc((size_t)512 * 512 * 2);
  __half* qkcatH = (__half*)alloc((size_t)4096 * 512 * 2);

  hipMemsetAsync(bcast, 0, (size_t)NGRP * 2 * 512 * 8, stream);
  conv_f16_kernel<<<(VCAB * 256 / 4 + 255) / 256, 256, 0, stream>>>(emb, embH, VCAB * 256 / 4);
  conv_f16_kernel<<<(1536 * 256 / 4 + 255) / 256, 256, 0, stream>>>(w_ih, w_ihH, 1536 * 256 / 4);
  prep_kernel<<<256, 256, 0, stream>>>(wq, wk, wh, bq, bk, bh, WcatH, biascat);
  // gx = emb[ids] @ w_ih^T + b_ih
  mfma_gemm_kernel<<<dim3(1536 / 128, 4096 / 128), 256, 0, stream>>>(
      embH, w_ihH, b_ih, gx, nullptr, 4096, 1536, 256, 256, 1536, ids);
  gru_kernel<<<NGRP * GRU_WGS, 512, 0, stream>>>(gx, w_hh, b_hh, statesH, bcast);
  // fused q|k|h_emb projection: qkcat f32 (q,k) + qkcatH f16 (h_emb for base GEMM)
  mfma_gemm_kernel<<<dim3(512 / 128, 4096 / 128), 256, 0, stream>>>(
      statesH, WcatH, biascat, qkcat, qkcatH, 4096, 512, 512, 512, 512, nullptr);
  // base logits: A = h_emb slice of qkcatH (cols 256..511, row stride 512)
  mfma_gemm_kernel<<<dim3(VCAB / 128, 4096 / 128), 256, 0, stream>>>(
      qkcatH + 256, embH, outb, out, nullptr, 4096, VCAB, 256, 512, VCAB, nullptr);
  attn_kernel<<<4096, 128, 0, stream>>>(qkcat, statesH, wg, bg, ids, memsc, out);
}

// Round 15
// 649.123 us; speedup vs baseline: 1.2496x; 1.2466x over previous
//
#include <hip/hip_runtime.h>
#include <hip/hip_fp16.h>

#define L_SZ 2048
#define VCAB 32000
#define GRU_WGS 16
#define NGRP 16
#define CHUNK 128
#define WARM 96
#define PF 12
#define RING 16

typedef __attribute__((ext_vector_type(8))) _Float16 f16x8;
typedef __attribute__((ext_vector_type(4))) float f32x4;

// ---------------- f32 -> f16 conversion (4 elems/thread) ----------------
__global__ __launch_bounds__(256) void conv_f16_kernel(const float* __restrict__ in,
                                                       __half* __restrict__ out, int n4) {
  int i = blockIdx.x * 256 + threadIdx.x;
  if (i >= n4) return;
  float4 v = ((const float4*)in)[i];
  __half2 a = __floats2half2_rn(v.x, v.y);
  __half2 b = __floats2half2_rn(v.z, v.w);
  uint2 u;
  u.x = *(unsigned*)&a;
  u.y = *(unsigned*)&b;
  ((uint2*)out)[i] = u;
}

// ---------------- prep: Wcat=[wq;wk;wh] f16 + biascat=[bq;bk;bh] f32, one launch ----------------
__global__ __launch_bounds__(256) void prep_kernel(const float* __restrict__ wq,
                                                   const float* __restrict__ wk,
                                                   const float* __restrict__ wh,
                                                   const float* __restrict__ bq,
                                                   const float* __restrict__ bk,
                                                   const float* __restrict__ bh,
                                                   __half* __restrict__ Wcat,
                                                   float* __restrict__ biascat) {
  int idx = blockIdx.x * 256 + threadIdx.x;   // 0..65535 (512*512/4)
  int e = idx * 4;
  int row = e >> 9, col = e & 511;
  const float* src = (row < 128) ? &wq[row * 512 + col]
                   : (row < 256) ? &wk[(row - 128) * 512 + col]
                                 : &wh[(row - 256) * 512 + col];
  float4 v = *(const float4*)src;
  __half2 a = __floats2half2_rn(v.x, v.y);
  __half2 b = __floats2half2_rn(v.z, v.w);
  uint2 u;
  u.x = *(unsigned*)&a;
  u.y = *(unsigned*)&b;
  ((uint2*)Wcat)[idx] = u;
  if (idx < 512)
    biascat[idx] = (idx < 128) ? bq[idx] : (idx < 256) ? bk[idx - 128] : bh[idx - 256];
}

// ---------------- generic MFMA GEMM, global_load_lds staging, XCD-swizzled ----------------
// C[m][n] = bias[n] + A_f16[row(m)] . W_f16[n]; A row stride lda; W row stride K.
__global__ __launch_bounds__(256) void mfma_gemm_kernel(const __half* __restrict__ A,
                                                        const __half* __restrict__ W,
                                                        const float* __restrict__ bias,
                                                        float* __restrict__ C,
                                                        __half* __restrict__ C16,
                                                        int M, int N, int K, int lda, int ldc,
                                                        const int* __restrict__ gather) {
  __shared__ __align__(16) __half Al[128 * 32];
  __shared__ __align__(16) __half Wl[128 * 32];
  const int tid = threadIdx.x;
  const int nbx = gridDim.x;
  int flat = blockIdx.y * nbx + blockIdx.x;
  int cpx = (nbx * gridDim.y) >> 3;
  int swz = (flat & 7) * cpx + (flat >> 3);
  const int n0 = (swz % nbx) * 128, m0 = (swz / nbx) * 128;
  const int lane = tid & 63, wave = tid >> 6;
  const int wm = wave >> 1, wn = wave & 1;
  const int fr = lane & 15, fk = (lane >> 4) * 8;
  const int r0 = tid >> 2, q0 = tid & 3;
  const int r1 = (tid + 256) >> 2, q1 = tid & 3;
  const int arow0 = gather ? gather[m0 + r0] : (m0 + r0);
  const int arow1 = gather ? gather[m0 + r1] : (m0 + r1);
  __half* a0d = &Al[wave * 512];
  __half* a1d = &Al[wave * 512 + 2048];
  __half* w0d = &Wl[wave * 512];
  __half* w1d = &Wl[wave * 512 + 2048];

  f32x4 acc[4][4];
#pragma unroll
  for (int i = 0; i < 4; ++i)
#pragma unroll
    for (int j = 0; j < 4; ++j) acc[i][j] = (f32x4){0.f, 0.f, 0.f, 0.f};

  for (int kt = 0; kt < K; kt += 32) {
    __builtin_amdgcn_global_load_lds((const unsigned int*)(A + (size_t)arow0 * lda + kt + q0 * 8),
                                     (unsigned int*)a0d, 16, 0, 0);
    __builtin_amdgcn_global_load_lds((const unsigned int*)(A + (size_t)arow1 * lda + kt + q1 * 8),
                                     (unsigned int*)a1d, 16, 0, 0);
    __builtin_amdgcn_global_load_lds((const unsigned int*)(W + (size_t)(n0 + r0) * K + kt + q0 * 8),
                                     (unsigned int*)w0d, 16, 0, 0);
    __builtin_amdgcn_global_load_lds((const unsigned int*)(W + (size_t)(n0 + r1) * K + kt + q1 * 8),
                                     (unsigned int*)w1d, 16, 0, 0);
    __syncthreads();
    f16x8 af[4], bfv[4];
#pragma unroll
    for (int mf = 0; mf < 4; ++mf) af[mf] = *(const f16x8*)&Al[(wm * 64 + mf * 16 + fr) * 32 + fk];
#pragma unroll
    for (int nf = 0; nf < 4; ++nf) bfv[nf] = *(const f16x8*)&Wl[(wn * 64 + nf * 16 + fr) * 32 + fk];
#pragma unroll
    for (int mf = 0; mf < 4; ++mf)
#pragma unroll
      for (int nf = 0; nf < 4; ++nf)
        acc[mf][nf] = __builtin_amdgcn_mfma_f32_16x16x32_f16(af[mf], bfv[nf], acc[mf][nf], 0, 0, 0);
    __syncthreads();
  }
  const int r4 = (lane >> 4) * 4;
#pragma unroll
  for (int mf = 0; mf < 4; ++mf)
#pragma unroll
    for (int nf = 0; nf < 4; ++nf)
#pragma unroll
      for (int v = 0; v < 4; ++v) {
        int m = m0 + wm * 64 + mf * 16 + r4 + v;
        int n = n0 + wn * 64 + nf * 16 + (lane & 15);
        float val = acc[mf][nf][v] + bias[n];
        if (C) C[(size_t)m * ldc + n] = val;
        if (C16) C16[(size_t)m * ldc + n] = __float2half(val);
      }
}

// ---------------- GRU: 16 chunk-groups x 16 WGs (1 block/CU), warmup-chunked ----------------
// Reverted to r11 geometry (GWS=16: VGPR 100, no spill; GWS=8 needed 240 VGPRs and the
// toolchain pinned the cap at 128 regardless of __launch_bounds__ hints -> scratch spill).
// Group g computes steps [t0, g*128+128), t0 = max(0, g*128-WARM); stores [g*128, ...).
__global__ __launch_bounds__(512) void gru_kernel(const float* __restrict__ gx,     // [B][L][1536]
                                                  const float* __restrict__ w_hh,   // [1536][512]
                                                  const float* __restrict__ b_hh,   // [1536]
                                                  __half* __restrict__ statesH,     // [B][L][512] f16
                                                  unsigned long long* __restrict__ bcast) { // [NGRP][2][512]
  const int tid = threadIdx.x;
  const int blk = blockIdx.x;
  const int g = blk >> 4;              // chunk-group 0..15
  const int w = blk & 15;              // worker rank within group
  const int c0 = g * CHUNK;            // chunk start (stored range)
  const int t0 = (c0 >= WARM) ? (c0 - WARM) : 0;
  const int t_end = c0 + CHUNK;
  const int nsteps = t_end - t0;
  unsigned long long* bc = bcast + (size_t)g * 2 * 512;

  __shared__ __align__(16) __half h16[2][512];
  __shared__ __align__(16) float ghp[4][2][96];          // [k-wave][batch][row]
  __shared__ __align__(16) float gxring[RING][2][3][32]; // [slot][batch][gate][unit]
  const int lane = tid & 63;
  const int wave = tid >> 6;
  const int fr = lane & 15, fkg = lane >> 4;

  // ---- waves 0-3: stage weight K-slice into registers ----
  f16x8 wreg[6][4];
  if (wave < 4) {
#pragma unroll
    for (int tile = 0; tile < 6; ++tile) {
      int r = tile * 16 + fr;          // 0..95
      int gg = r >> 5, kl = r & 31;
      const float* wrow = w_hh + (size_t)(gg * 512 + w * 32 + kl) * 512 + wave * 128;
#pragma unroll
      for (int j = 0; j < 4; ++j) {
        const float* p = wrow + j * 32 + fkg * 8;
        float4 x = *(const float4*)p;
        float4 y = *(const float4*)(p + 4);
        f16x8 v;
        v[0] = (_Float16)x.x; v[1] = (_Float16)x.y; v[2] = (_Float16)x.z; v[3] = (_Float16)x.w;
        v[4] = (_Float16)y.x; v[5] = (_Float16)y.y; v[6] = (_Float16)y.z; v[7] = (_Float16)y.w;
        wreg[tile][j] = v;
      }
    }
  }
  for (int i = tid; i < 1024; i += 512) h16[i >> 9][i & 511] = __float2half(0.f);

  // ---- ring prologue: slots 0..PF-1 = gx[t0 .. t0+PF) ----
  for (int i = tid; i < PF * 192; i += 512) {
    int s = i / 192, r = i % 192;
    int pb = r / 96, pg = (r - pb * 96) >> 5, pu = r & 31;
    gxring[s][pb][pg][pu] = gx[((size_t)pb * L_SZ + (t0 + s)) * 1536 + pg * 512 + w * 32 + pu];
  }

  // ---- wave 4: prefetch registers = gx[t0+PF] ----
  const int pb4 = lane >> 5, pu4 = lane & 31;
  float Rr = 0.f, Rz = 0.f, Rn = 0.f;
  if (wave == 4) {
    const float* gp = gx + ((size_t)pb4 * L_SZ + (t0 + PF)) * 1536 + w * 32 + pu4;
    Rr = gp[0]; Rz = gp[512]; Rn = gp[1024];
  }

  // ---- wave 7: gate setup ----
  const int gb = lane >> 5, gk = lane & 31;
  const int kglob = w * 32 + gk;
  float bhr = 0.f, bhz = 0.f, bhn = 0.f, hp = 0.f;
  if (wave == 7) { bhr = b_hh[kglob]; bhz = b_hh[512 + kglob]; bhn = b_hh[1024 + kglob]; }

  // ---- waves 5-6: spinner word mapping (480 words, 4 per thread) ----
  const int sidx = tid - 320;          // 0..127
  int r0s = 0, j0s = 0, r1s = 0, j1s = 0, r2s = 0, j2s = 0, r3s = 0, j3s = 0;
  bool has3 = false;
  if (wave >= 5 && wave < 7) {
    int i0 = sidx, i1 = sidx + 128, i2 = sidx + 256, i3 = sidx + 384;
    r0s = i0 >> 5; r0s += (r0s >= w); j0s = i0 & 31;
    r1s = i1 >> 5; r1s += (r1s >= w); j1s = i1 & 31;
    r2s = i2 >> 5; r2s += (r2s >= w); j2s = i2 & 31;
    has3 = (i3 < 480);
    if (has3) { r3s = i3 >> 5; r3s += (r3s >= w); j3s = i3 & 31; }
    else { r3s = r0s; j3s = j0s; }     // duplicate word 0 (always matches together)
  }
  __syncthreads();

  for (int ts = 0; ts < nsteps; ++ts) {
    const int t = t0 + ts;
    __half hsave = __float2half(0.f);
    // ---- phase 1 ----
    if (wave < 4) {
      f32x4 acc[6];
#pragma unroll
      for (int tile = 0; tile < 6; ++tile) acc[tile] = (f32x4){0.f, 0.f, 0.f, 0.f};
#pragma unroll
      for (int j = 0; j < 4; ++j) {
        int kt = wave * 4 + j;
        f16x8 bf = *(const f16x8*)&h16[fr & 1][kt * 32 + fkg * 8];
#pragma unroll
        for (int tile = 0; tile < 6; ++tile)
          acc[tile] = __builtin_amdgcn_mfma_f32_16x16x32_f16(wreg[tile][j], bf, acc[tile], 0, 0, 0);
      }
      if (fr < 2) {
#pragma unroll
        for (int tile = 0; tile < 6; ++tile)
          *(f32x4*)&ghp[wave][fr][tile * 16 + fkg * 4] = acc[tile];
      }
    } else if (wave == 4) {
      hsave = h16[pb4][w * 32 + pu4];   // h_{t-1}, stable until phase 2
    }
    __syncthreads();  // sync1: ghp ready; h16 reads done

    // ---- phase 2 ----
    if (wave == 7) {
      int slot = ts & (RING - 1);
      float gxr = gxring[slot][gb][0][gk];
      float gxz = gxring[slot][gb][1][gk];
      float gxn = gxring[slot][gb][2][gk];
      float ghr = ghp[0][gb][gk] + ghp[1][gb][gk] + ghp[2][gb][gk] + ghp[3][gb][gk];
      float ghz = ghp[0][gb][32 + gk] + ghp[1][gb][32 + gk] + ghp[2][gb][32 + gk] + ghp[3][gb][32 + gk];
      float ghn = ghp[0][gb][64 + gk] + ghp[1][gb][64 + gk] + ghp[2][gb][64 + gk] + ghp[3][gb][64 + gk];
      float rr = 1.f / (1.f + __expf(-(gxr + ghr + bhr)));
      float zz = 1.f / (1.f + __expf(-(gxz + ghz + bhz)));
      float y = gxn + rr * (ghn + bhn);
      float e2 = __expf(2.f * y);
      float nn = 1.f - 2.f / (e2 + 1.f);   // tanh(y), saturates correctly
      float hv = (1.f - zz) * nn + zz * hp;
      hp = hv;
      __half hvh = __float2half(hv);
      h16[gb][kglob] = hvh;
      float hvo = __shfl(hv, lane ^ 32);
      if (gb == 0) {
        unsigned long long pk = ((unsigned long long)(unsigned)(ts + 1) << 32)
                              | (unsigned long long)__half_as_ushort(hvh)
                              | ((unsigned long long)__half_as_ushort(__float2half(hvo)) << 16);
        __hip_atomic_store(&bc[(size_t)(ts & 1) * 512 + w * 32 + gk], pk,
                           __ATOMIC_RELAXED, __HIP_MEMORY_SCOPE_AGENT);
      }
    } else if (wave == 4) {
      if (t > c0) statesH[((size_t)pb4 * L_SZ + (t - 1)) * 512 + w * 32 + pu4] = hsave;
      int slot = (ts + PF) & (RING - 1);
      gxring[slot][pb4][0][pu4] = Rr;
      gxring[slot][pb4][1][pu4] = Rz;
      gxring[slot][pb4][2][pu4] = Rn;
      int tg = t0 + ts + PF + 1; if (tg > t_end - 1) tg = t_end - 1;
      const float* gp = gx + ((size_t)pb4 * L_SZ + tg) * 1536 + w * 32 + pu4;
      Rr = gp[0]; Rz = gp[512]; Rn = gp[1024];
    } else if (wave >= 5) {
      const unsigned want = (unsigned)(ts + 1);
      const unsigned long long* base = bc + (size_t)(ts & 1) * 512;
      const unsigned long long* a0 = base + r0s * 32 + j0s;
      const unsigned long long* a1 = base + r1s * 32 + j1s;
      const unsigned long long* a2 = base + r2s * 32 + j2s;
      const unsigned long long* a3 = base + r3s * 32 + j3s;
      unsigned long long v0, v1, v2, v3;
      do {
        v0 = __hip_atomic_load(a0, __ATOMIC_RELAXED, __HIP_MEMORY_SCOPE_AGENT);
        v1 = __hip_atomic_load(a1, __ATOMIC_RELAXED, __HIP_MEMORY_SCOPE_AGENT);
        v2 = __hip_atomic_load(a2, __ATOMIC_RELAXED, __HIP_MEMORY_SCOPE_AGENT);
        v3 = has3 ? __hip_atomic_load(a3, __ATOMIC_RELAXED, __HIP_MEMORY_SCOPE_AGENT)
                  : ((unsigned long long)want << 32);
      } while ((unsigned)(v0 >> 32) != want || (unsigned)(v1 >> 32) != want ||
               (unsigned)(v2 >> 32) != want || (unsigned)(v3 >> 32) != want);
      h16[0][r0s * 32 + j0s] = __ushort_as_half((unsigned short)v0);
      h16[1][r0s * 32 + j0s] = __ushort_as_half((unsigned short)(v0 >> 16));
      h16[0][r1s * 32 + j1s] = __ushort_as_half((unsigned short)v1);
      h16[1][r1s * 32 + j1s] = __ushort_as_half((unsigned short)(v1 >> 16));
      h16[0][r2s * 32 + j2s] = __ushort_as_half((unsigned short)v2);
      h16[1][r2s * 32 + j2s] = __ushort_as_half((unsigned short)(v2 >> 16));
      if (has3) {
        h16[0][r3s * 32 + j3s] = __ushort_as_half((unsigned short)v3);
        h16[1][r3s * 32 + j3s] = __ushort_as_half((unsigned short)(v3 >> 16));
      }
    }
    __syncthreads();  // sync2: h16 complete for next step
  }
  if (wave == 4) {  // final state of this chunk
    __half hv = h16[pb4][w * 32 + pu4];
    statesH[((size_t)pb4 * L_SZ + (t_end - 1)) * 512 + w * 32 + pu4] = hv;
  }
}

// ---------------- windowed attention + scatter-add, gate computed inline ----------------
// q = qk[:, 0:128], k = qk[:, 128:256] with row stride 512
__global__ __launch_bounds__(128) void attn_kernel(const float* __restrict__ qk,
                                                   const __half* __restrict__ states,
                                                   const float* __restrict__ wg,
                                                   const float* __restrict__ bg,
                                                   const int* __restrict__ ids,
                                                   const float* __restrict__ mem_scale,
                                                   float* __restrict__ out) {
  __shared__ float qs[128];
  __shared__ float cm[2], cs[2], cg[2];
  const int bi = blockIdx.x;
  const int i = bi & (L_SZ - 1), b = bi >> 11;
  if (i == 0) return;
  const int w0 = (i > 128) ? (i - 128) : 0;
  const int wlen = i - w0;
  const int tid = threadIdx.x;
  const int ln = tid & 63, wv = tid >> 6;
  qs[tid] = qk[(size_t)bi * 512 + tid];
  // inline gate partial: dot(states[bi], wg), 4 elems/thread
  uint2 hv = *(const uint2*)&states[(size_t)bi * 512 + tid * 4];
  float2 f01 = __half22float2(*(__half2*)&hv.x);
  float2 f23 = __half22float2(*(__half2*)&hv.y);
  float gpart = f01.x * wg[tid * 4] + f01.y * wg[tid * 4 + 1] +
                f23.x * wg[tid * 4 + 2] + f23.y * wg[tid * 4 + 3];
#pragma unroll
  for (int off = 32; off; off >>= 1) gpart += __shfl_xor(gpart, off);
  if (ln == 0) cg[wv] = gpart;
  __syncthreads();
  float s = -1e30f;
  if (tid < wlen) {
    const float4* kr = (const float4*)&qk[(size_t)(b * L_SZ + w0 + tid) * 512 + 128];
    const float4* qr = (const float4*)qs;
    float a0 = 0.f, a1 = 0.f, a2 = 0.f, a3 = 0.f;
#pragma unroll 8
    for (int c = 0; c < 32; ++c) {
      float4 kv = kr[c];
      float4 qv = qr[c];
      a0 = fmaf(kv.x, qv.x, a0); a1 = fmaf(kv.y, qv.y, a1);
      a2 = fmaf(kv.z, qv.z, a2); a3 = fmaf(kv.w, qv.w, a3);
    }
    s = ((a0 + a1) + (a2 + a3)) * 0.08838834764831845f;  // 1/sqrt(128)
  }
  float m = s;
#pragma unroll
  for (int off = 32; off; off >>= 1) m = fmaxf(m, __shfl_xor(m, off));
  if (ln == 0) cm[wv] = m;
  __syncthreads();
  float mx = fmaxf(cm[0], cm[1]);
  float p = (tid < wlen) ? __expf(s - mx) : 0.f;
  float sum = p;
#pragma unroll
  for (int off = 32; off; off >>= 1) sum += __shfl_xor(sum, off);
  if (ln == 0) cs[wv] = sum;
  __syncthreads();
  float gateval = 1.f / (1.f + __expf(-(cg[0] + cg[1] + bg[0])));
  float inv = 1.f / (cs[0] + cs[1]);
  if (tid < wlen) {
    float val = p * inv * gateval * mem_scale[0];
    int id = ids[b * L_SZ + w0 + tid];
    atomicAdd(&out[(size_t)bi * VCAB + id], val);
  }
}

// ---------------- launch ----------------
extern "C" void kernel_launch(void* const* d_in, const int* in_sizes, int n_in,
                              void* d_out, int out_size, void* d_ws, size_t ws_size,
                              hipStream_t stream) {
  (void)in_sizes; (void)n_in; (void)out_size; (void)ws_size;
  const int* ids = (const int*)d_in[0];
  const float* emb = (const float*)d_in[1];
  const float* w_ih = (const float*)d_in[2];
  const float* w_hh = (const float*)d_in[3];
  const float* b_ih = (const float*)d_in[4];
  const float* b_hh = (const float*)d_in[5];
  const float* wq = (const float*)d_in[6];
  const float* bq = (const float*)d_in[7];
  const float* wk = (const float*)d_in[8];
  const float* bk = (const float*)d_in[9];
  const float* wg = (const float*)d_in[10];
  const float* bg = (const float*)d_in[11];
  const float* wh = (const float*)d_in[12];
  const float* bh = (const float*)d_in[13];
  const float* outb = (const float*)d_in[14];
  const float* memsc = (const float*)d_in[15];
  float* out = (float*)d_out;

  char* ws = (char*)d_ws;
  size_t off = 0;
  auto alloc = [&](size_t bytes) {
    void* p = ws + off;
    off = (off + bytes + 255) & ~(size_t)255;
    return p;
  };
  unsigned long long* bcast = (unsigned long long*)alloc((size_t)NGRP * 2 * 512 * 8);
  float* gx = (float*)alloc((size_t)4096 * 1536 * 4);
  float* biascat = (float*)alloc(512 * 4);
  float* qkcat = (float*)alloc((size_t)4096 * 512 * 4);
  __half* embH = (__half*)alloc((size_t)VCAB * 256 * 2);
  __half* w_ihH = (__half*)alloc((size_t)1536 * 256 * 2);
  __half* statesH = (__half*)alloc((size_t)4096 * 512 * 2);
  __half* WcatH = (__half*)alloc((size_t)512 * 512 * 2);
  __half* qkcatH = (__half*)alloc((size_t)4096 * 512 * 2);

  hipMemsetAsync(bcast, 0, (size_t)NGRP * 2 * 512 * 8, stream);
  conv_f16_kernel<<<(VCAB * 256 / 4 + 255) / 256, 256, 0, stream>>>(emb, embH, VCAB * 256 / 4);
  conv_f16_kernel<<<(1536 * 256 / 4 + 255) / 256, 256, 0, stream>>>(w_ih, w_ihH, 1536 * 256 / 4);
  prep_kernel<<<256, 256, 0, stream>>>(wq, wk, wh, bq, bk, bh, WcatH, biascat);
  // gx = emb[ids] @ w_ih^T + b_ih
  mfma_gemm_kernel<<<dim3(1536 / 128, 4096 / 128), 256, 0, stream>>>(
      embH, w_ihH, b_ih, gx, nullptr, 4096, 1536, 256, 256, 1536, ids);
  gru_kernel<<<NGRP * GRU_WGS, 512, 0, stream>>>(gx, w_hh, b_hh, statesH, bcast);
  // fused q|k|h_emb projection: qkcat f32 (q,k) + qkcatH f16 (h_emb for base GEMM)
  mfma_gemm_kernel<<<dim3(512 / 128, 4096 / 128), 256, 0, stream>>>(
      statesH, WcatH, biascat, qkcat, qkcatH, 4096, 512, 512, 512, 512, nullptr);
  // base logits: A = h_emb slice of qkcatH (cols 256..511, row stride 512)
  mfma_gemm_kernel<<<dim3(VCAB / 128, 4096 / 128), 256, 0, stream>>>(
      qkcatH + 256, embH, outb, out, nullptr, 4096, VCAB, 256, 512, VCAB, nullptr);
  attn_kernel<<<4096, 128, 0, stream>>>(qkcat, statesH, wg, bg, ids, memsc, out);
}

// Round 16
// 648.901 us; speedup vs baseline: 1.2500x; 1.0003x over previous
//
#include <hip/hip_runtime.h>
#include <hip/hip_fp16.h>

#define L_SZ 2048
#define VCAB 32000
#define GRU_WGS 16
#define NGRP 16
#define CHUNK 128
#define WARM 96
#define PF 12
#define RING 16

typedef __attribute__((ext_vector_type(8))) _Float16 f16x8;
typedef __attribute__((ext_vector_type(4))) float f32x4;

// ---------------- f32 -> f16 conversion (4 elems/thread) ----------------
__global__ __launch_bounds__(256) void conv_f16_kernel(const float* __restrict__ in,
                                                       __half* __restrict__ out, int n4) {
  int i = blockIdx.x * 256 + threadIdx.x;
  if (i >= n4) return;
  float4 v = ((const float4*)in)[i];
  __half2 a = __floats2half2_rn(v.x, v.y);
  __half2 b = __floats2half2_rn(v.z, v.w);
  uint2 u;
  u.x = *(unsigned*)&a;
  u.y = *(unsigned*)&b;
  ((uint2*)out)[i] = u;
}

// ---------------- prep: Wcat=[wq;wk;wh] f16 + biascat=[bq;bk;bh] f32, one launch ----------------
__global__ __launch_bounds__(256) void prep_kernel(const float* __restrict__ wq,
                                                   const float* __restrict__ wk,
                                                   const float* __restrict__ wh,
                                                   const float* __restrict__ bq,
                                                   const float* __restrict__ bk,
                                                   const float* __restrict__ bh,
                                                   __half* __restrict__ Wcat,
                                                   float* __restrict__ biascat) {
  int idx = blockIdx.x * 256 + threadIdx.x;   // 0..65535 (512*512/4)
  int e = idx * 4;
  int row = e >> 9, col = e & 511;
  const float* src = (row < 128) ? &wq[row * 512 + col]
                   : (row < 256) ? &wk[(row - 128) * 512 + col]
                                 : &wh[(row - 256) * 512 + col];
  float4 v = *(const float4*)src;
  __half2 a = __floats2half2_rn(v.x, v.y);
  __half2 b = __floats2half2_rn(v.z, v.w);
  uint2 u;
  u.x = *(unsigned*)&a;
  u.y = *(unsigned*)&b;
  ((uint2*)Wcat)[idx] = u;
  if (idx < 512)
    biascat[idx] = (idx < 128) ? bq[idx] : (idx < 256) ? bk[idx - 128] : bh[idx - 256];
}

// ---------------- generic MFMA GEMM, global_load_lds staging, XCD-swizzled ----------------
// C[m][n] = bias[n] + A_f16[row(m)] . W_f16[n]; A row stride lda; W row stride K.
__global__ __launch_bounds__(256) void mfma_gemm_kernel(const __half* __restrict__ A,
                                                        const __half* __restrict__ W,
                                                        const float* __restrict__ bias,
                                                        float* __restrict__ C,
                                                        __half* __restrict__ C16,
                                                        int M, int N, int K, int lda, int ldc,
                                                        const int* __restrict__ gather) {
  __shared__ __align__(16) __half Al[128 * 32];
  __shared__ __align__(16) __half Wl[128 * 32];
  const int tid = threadIdx.x;
  const int nbx = gridDim.x;
  int flat = blockIdx.y * nbx + blockIdx.x;
  int cpx = (nbx * gridDim.y) >> 3;
  int swz = (flat & 7) * cpx + (flat >> 3);
  const int n0 = (swz % nbx) * 128, m0 = (swz / nbx) * 128;
  const int lane = tid & 63, wave = tid >> 6;
  const int wm = wave >> 1, wn = wave & 1;
  const int fr = lane & 15, fk = (lane >> 4) * 8;
  const int r0 = tid >> 2, q0 = tid & 3;
  const int r1 = (tid + 256) >> 2, q1 = tid & 3;
  const int arow0 = gather ? gather[m0 + r0] : (m0 + r0);
  const int arow1 = gather ? gather[m0 + r1] : (m0 + r1);
  __half* a0d = &Al[wave * 512];
  __half* a1d = &Al[wave * 512 + 2048];
  __half* w0d = &Wl[wave * 512];
  __half* w1d = &Wl[wave * 512 + 2048];

  f32x4 acc[4][4];
#pragma unroll
  for (int i = 0; i < 4; ++i)
#pragma unroll
    for (int j = 0; j < 4; ++j) acc[i][j] = (f32x4){0.f, 0.f, 0.f, 0.f};

  for (int kt = 0; kt < K; kt += 32) {
    __builtin_amdgcn_global_load_lds((const unsigned int*)(A + (size_t)arow0 * lda + kt + q0 * 8),
                                     (unsigned int*)a0d, 16, 0, 0);
    __builtin_amdgcn_global_load_lds((const unsigned int*)(A + (size_t)arow1 * lda + kt + q1 * 8),
                                     (unsigned int*)a1d, 16, 0, 0);
    __builtin_amdgcn_global_load_lds((const unsigned int*)(W + (size_t)(n0 + r0) * K + kt + q0 * 8),
                                     (unsigned int*)w0d, 16, 0, 0);
    __builtin_amdgcn_global_load_lds((const unsigned int*)(W + (size_t)(n0 + r1) * K + kt + q1 * 8),
                                     (unsigned int*)w1d, 16, 0, 0);
    __syncthreads();
    f16x8 af[4], bfv[4];
#pragma unroll
    for (int mf = 0; mf < 4; ++mf) af[mf] = *(const f16x8*)&Al[(wm * 64 + mf * 16 + fr) * 32 + fk];
#pragma unroll
    for (int nf = 0; nf < 4; ++nf) bfv[nf] = *(const f16x8*)&Wl[(wn * 64 + nf * 16 + fr) * 32 + fk];
#pragma unroll
    for (int mf = 0; mf < 4; ++mf)
#pragma unroll
      for (int nf = 0; nf < 4; ++nf)
        acc[mf][nf] = __builtin_amdgcn_mfma_f32_16x16x32_f16(af[mf], bfv[nf], acc[mf][nf], 0, 0, 0);
    __syncthreads();
  }
  const int r4 = (lane >> 4) * 4;
#pragma unroll
  for (int mf = 0; mf < 4; ++mf)
#pragma unroll
    for (int nf = 0; nf < 4; ++nf)
#pragma unroll
      for (int v = 0; v < 4; ++v) {
        int m = m0 + wm * 64 + mf * 16 + r4 + v;
        int n = n0 + wn * 64 + nf * 16 + (lane & 15);
        float val = acc[mf][nf][v] + bias[n];
        if (C) C[(size_t)m * ldc + n] = val;
        if (C16) C16[(size_t)m * ldc + n] = __float2half(val);
      }
}

// ---------------- GRU: 16 chunk-groups x 16 WGs (1 block/CU), warmup-chunked ----------------
// Reverted to r11 geometry (GWS=16: VGPR 100, no spill; GWS=8 needed 240 VGPRs and the
// toolchain pinned the cap at 128 regardless of __launch_bounds__ hints -> scratch spill).
// Group g computes steps [t0, g*128+128), t0 = max(0, g*128-WARM); stores [g*128, ...).
__global__ __launch_bounds__(512) void gru_kernel(const float* __restrict__ gx,     // [B][L][1536]
                                                  const float* __restrict__ w_hh,   // [1536][512]
                                                  const float* __restrict__ b_hh,   // [1536]
                                                  __half* __restrict__ statesH,     // [B][L][512] f16
                                                  unsigned long long* __restrict__ bcast) { // [NGRP][2][512]
  const int tid = threadIdx.x;
  const int blk = blockIdx.x;
  const int g = blk >> 4;              // chunk-group 0..15
  const int w = blk & 15;              // worker rank within group
  const int c0 = g * CHUNK;            // chunk start (stored range)
  const int t0 = (c0 >= WARM) ? (c0 - WARM) : 0;
  const int t_end = c0 + CHUNK;
  const int nsteps = t_end - t0;
  unsigned long long* bc = bcast + (size_t)g * 2 * 512;

  __shared__ __align__(16) __half h16[2][512];
  __shared__ __align__(16) float ghp[4][2][96];          // [k-wave][batch][row]
  __shared__ __align__(16) float gxring[RING][2][3][32]; // [slot][batch][gate][unit]
  const int lane = tid & 63;
  const int wave = tid >> 6;
  const int fr = lane & 15, fkg = lane >> 4;

  // ---- waves 0-3: stage weight K-slice into registers ----
  f16x8 wreg[6][4];
  if (wave < 4) {
#pragma unroll
    for (int tile = 0; tile < 6; ++tile) {
      int r = tile * 16 + fr;          // 0..95
      int gg = r >> 5, kl = r & 31;
      const float* wrow = w_hh + (size_t)(gg * 512 + w * 32 + kl) * 512 + wave * 128;
#pragma unroll
      for (int j = 0; j < 4; ++j) {
        const float* p = wrow + j * 32 + fkg * 8;
        float4 x = *(const float4*)p;
        float4 y = *(const float4*)(p + 4);
        f16x8 v;
        v[0] = (_Float16)x.x; v[1] = (_Float16)x.y; v[2] = (_Float16)x.z; v[3] = (_Float16)x.w;
        v[4] = (_Float16)y.x; v[5] = (_Float16)y.y; v[6] = (_Float16)y.z; v[7] = (_Float16)y.w;
        wreg[tile][j] = v;
      }
    }
  }
  for (int i = tid; i < 1024; i += 512) h16[i >> 9][i & 511] = __float2half(0.f);

  // ---- ring prologue: slots 0..PF-1 = gx[t0 .. t0+PF) ----
  for (int i = tid; i < PF * 192; i += 512) {
    int s = i / 192, r = i % 192;
    int pb = r / 96, pg = (r - pb * 96) >> 5, pu = r & 31;
    gxring[s][pb][pg][pu] = gx[((size_t)pb * L_SZ + (t0 + s)) * 1536 + pg * 512 + w * 32 + pu];
  }

  // ---- wave 4: prefetch registers = gx[t0+PF] ----
  const int pb4 = lane >> 5, pu4 = lane & 31;
  float Rr = 0.f, Rz = 0.f, Rn = 0.f;
  if (wave == 4) {
    const float* gp = gx + ((size_t)pb4 * L_SZ + (t0 + PF)) * 1536 + w * 32 + pu4;
    Rr = gp[0]; Rz = gp[512]; Rn = gp[1024];
  }

  // ---- wave 7: gate setup ----
  const int gb = lane >> 5, gk = lane & 31;
  const int kglob = w * 32 + gk;
  float bhr = 0.f, bhz = 0.f, bhn = 0.f, hp = 0.f;
  if (wave == 7) { bhr = b_hh[kglob]; bhz = b_hh[512 + kglob]; bhn = b_hh[1024 + kglob]; }

  // ---- waves 5-6: spinner word mapping (480 words, 4 per thread) ----
  const int sidx = tid - 320;          // 0..127
  int r0s = 0, j0s = 0, r1s = 0, j1s = 0, r2s = 0, j2s = 0, r3s = 0, j3s = 0;
  bool has3 = false;
  if (wave >= 5 && wave < 7) {
    int i0 = sidx, i1 = sidx + 128, i2 = sidx + 256, i3 = sidx + 384;
    r0s = i0 >> 5; r0s += (r0s >= w); j0s = i0 & 31;
    r1s = i1 >> 5; r1s += (r1s >= w); j1s = i1 & 31;
    r2s = i2 >> 5; r2s += (r2s >= w); j2s = i2 & 31;
    has3 = (i3 < 480);
    if (has3) { r3s = i3 >> 5; r3s += (r3s >= w); j3s = i3 & 31; }
    else { r3s = r0s; j3s = j0s; }     // duplicate word 0 (always matches together)
  }
  __syncthreads();

  for (int ts = 0; ts < nsteps; ++ts) {
    const int t = t0 + ts;
    __half hsave = __float2half(0.f);
    // ---- phase 1 ----
    if (wave < 4) {
      f32x4 acc[6];
#pragma unroll
      for (int tile = 0; tile < 6; ++tile) acc[tile] = (f32x4){0.f, 0.f, 0.f, 0.f};
#pragma unroll
      for (int j = 0; j < 4; ++j) {
        int kt = wave * 4 + j;
        f16x8 bf = *(const f16x8*)&h16[fr & 1][kt * 32 + fkg * 8];
#pragma unroll
        for (int tile = 0; tile < 6; ++tile)
          acc[tile] = __builtin_amdgcn_mfma_f32_16x16x32_f16(wreg[tile][j], bf, acc[tile], 0, 0, 0);
      }
      if (fr < 2) {
#pragma unroll
        for (int tile = 0; tile < 6; ++tile)
          *(f32x4*)&ghp[wave][fr][tile * 16 + fkg * 4] = acc[tile];
      }
    } else if (wave == 4) {
      hsave = h16[pb4][w * 32 + pu4];   // h_{t-1}, stable until phase 2
    }
    __syncthreads();  // sync1: ghp ready; h16 reads done

    // ---- phase 2 ----
    if (wave == 7) {
      int slot = ts & (RING - 1);
      float gxr = gxring[slot][gb][0][gk];
      float gxz = gxring[slot][gb][1][gk];
      float gxn = gxring[slot][gb][2][gk];
      float ghr = ghp[0][gb][gk] + ghp[1][gb][gk] + ghp[2][gb][gk] + ghp[3][gb][gk];
      float ghz = ghp[0][gb][32 + gk] + ghp[1][gb][32 + gk] + ghp[2][gb][32 + gk] + ghp[3][gb][32 + gk];
      float ghn = ghp[0][gb][64 + gk] + ghp[1][gb][64 + gk] + ghp[2][gb][64 + gk] + ghp[3][gb][64 + gk];
      float rr = 1.f / (1.f + __expf(-(gxr + ghr + bhr)));
      float zz = 1.f / (1.f + __expf(-(gxz + ghz + bhz)));
      float y = gxn + rr * (ghn + bhn);
      float e2 = __expf(2.f * y);
      float nn = 1.f - 2.f / (e2 + 1.f);   // tanh(y), saturates correctly
      float hv = (1.f - zz) * nn + zz * hp;
      hp = hv;
      __half hvh = __float2half(hv);
      h16[gb][kglob] = hvh;
      float hvo = __shfl(hv, lane ^ 32);
      if (gb == 0) {
        unsigned long long pk = ((unsigned long long)(unsigned)(ts + 1) << 32)
                              | (unsigned long long)__half_as_ushort(hvh)
                              | ((unsigned long long)__half_as_ushort(__float2half(hvo)) << 16);
        __hip_atomic_store(&bc[(size_t)(ts & 1) * 512 + w * 32 + gk], pk,
                           __ATOMIC_RELAXED, __HIP_MEMORY_SCOPE_AGENT);
      }
    } else if (wave == 4) {
      if (t > c0) statesH[((size_t)pb4 * L_SZ + (t - 1)) * 512 + w * 32 + pu4] = hsave;
      int slot = (ts + PF) & (RING - 1);
      gxring[slot][pb4][0][pu4] = Rr;
      gxring[slot][pb4][1][pu4] = Rz;
      gxring[slot][pb4][2][pu4] = Rn;
      int tg = t0 + ts + PF + 1; if (tg > t_end - 1) tg = t_end - 1;
      const float* gp = gx + ((size_t)pb4 * L_SZ + tg) * 1536 + w * 32 + pu4;
      Rr = gp[0]; Rz = gp[512]; Rn = gp[1024];
    } else if (wave >= 5) {
      const unsigned want = (unsigned)(ts + 1);
      const unsigned long long* base = bc + (size_t)(ts & 1) * 512;
      const unsigned long long* a0 = base + r0s * 32 + j0s;
      const unsigned long long* a1 = base + r1s * 32 + j1s;
      const unsigned long long* a2 = base + r2s * 32 + j2s;
      const unsigned long long* a3 = base + r3s * 32 + j3s;
      unsigned long long v0, v1, v2, v3;
      do {
        v0 = __hip_atomic_load(a0, __ATOMIC_RELAXED, __HIP_MEMORY_SCOPE_AGENT);
        v1 = __hip_atomic_load(a1, __ATOMIC_RELAXED, __HIP_MEMORY_SCOPE_AGENT);
        v2 = __hip_atomic_load(a2, __ATOMIC_RELAXED, __HIP_MEMORY_SCOPE_AGENT);
        v3 = has3 ? __hip_atomic_load(a3, __ATOMIC_RELAXED, __HIP_MEMORY_SCOPE_AGENT)
                  : ((unsigned long long)want << 32);
      } while ((unsigned)(v0 >> 32) != want || (unsigned)(v1 >> 32) != want ||
               (unsigned)(v2 >> 32) != want || (unsigned)(v3 >> 32) != want);
      h16[0][r0s * 32 + j0s] = __ushort_as_half((unsigned short)v0);
      h16[1][r0s * 32 + j0s] = __ushort_as_half((unsigned short)(v0 >> 16));
      h16[0][r1s * 32 + j1s] = __ushort_as_half((unsigned short)v1);
      h16[1][r1s * 32 + j1s] = __ushort_as_half((unsigned short)(v1 >> 16));
      h16[0][r2s * 32 + j2s] = __ushort_as_half((unsigned short)v2);
      h16[1][r2s * 32 + j2s] = __ushort_as_half((unsigned short)(v2 >> 16));
      if (has3) {
        h16[0][r3s * 32 + j3s] = __ushort_as_half((unsigned short)v3);
        h16[1][r3s * 32 + j3s] = __ushort_as_half((unsigned short)(v3 >> 16));
      }
    }
    __syncthreads();  // sync2: h16 complete for next step
  }
  if (wave == 4) {  // final state of this chunk
    __half hv = h16[pb4][w * 32 + pu4];
    statesH[((size_t)pb4 * L_SZ + (t_end - 1)) * 512 + w * 32 + pu4] = hv;
  }
}

// ---------------- windowed attention + scatter-add, gate computed inline ----------------
// q = qk[:, 0:128], k = qk[:, 128:256] with row stride 512
__global__ __launch_bounds__(128) void attn_kernel(const float* __restrict__ qk,
                                                   const __half* __restrict__ states,
                                                   const float* __restrict__ wg,
                                                   const float* __restrict__ bg,
                                                   const int* __restrict__ ids,
                                                   const float* __restrict__ mem_scale,
                                                   float* __restrict__ out) {
  __shared__ float qs[128];
  __shared__ float cm[2], cs[2], cg[2];
  const int bi = blockIdx.x;
  const int i = bi & (L_SZ - 1), b = bi >> 11;
  if (i == 0) return;
  const int w0 = (i > 128) ? (i - 128) : 0;
  const int wlen = i - w0;
  const int tid = threadIdx.x;
  const int ln = tid & 63, wv = tid >> 6;
  qs[tid] = qk[(size_t)bi * 512 + tid];
  // inline gate partial: dot(states[bi], wg), 4 elems/thread
  uint2 hv = *(const uint2*)&states[(size_t)bi * 512 + tid * 4];
  float2 f01 = __half22float2(*(__half2*)&hv.x);
  float2 f23 = __half22float2(*(__half2*)&hv.y);
  float gpart = f01.x * wg[tid * 4] + f01.y * wg[tid * 4 + 1] +
                f23.x * wg[tid * 4 + 2] + f23.y * wg[tid * 4 + 3];
#pragma unroll
  for (int off = 32; off; off >>= 1) gpart += __shfl_xor(gpart, off);
  if (ln == 0) cg[wv] = gpart;
  __syncthreads();
  float s = -1e30f;
  if (tid < wlen) {
    const float4* kr = (const float4*)&qk[(size_t)(b * L_SZ + w0 + tid) * 512 + 128];
    const float4* qr = (const float4*)qs;
    float a0 = 0.f, a1 = 0.f, a2 = 0.f, a3 = 0.f;
#pragma unroll 8
    for (int c = 0; c < 32; ++c) {
      float4 kv = kr[c];
      float4 qv = qr[c];
      a0 = fmaf(kv.x, qv.x, a0); a1 = fmaf(kv.y, qv.y, a1);
      a2 = fmaf(kv.z, qv.z, a2); a3 = fmaf(kv.w, qv.w, a3);
    }
    s = ((a0 + a1) + (a2 + a3)) * 0.08838834764831845f;  // 1/sqrt(128)
  }
  float m = s;
#pragma unroll
  for (int off = 32; off; off >>= 1) m = fmaxf(m, __shfl_xor(m, off));
  if (ln == 0) cm[wv] = m;
  __syncthreads();
  float mx = fmaxf(cm[0], cm[1]);
  float p = (tid < wlen) ? __expf(s - mx) : 0.f;
  float sum = p;
#pragma unroll
  for (int off = 32; off; off >>= 1) sum += __shfl_xor(sum, off);
  if (ln == 0) cs[wv] = sum;
  __syncthreads();
  float gateval = 1.f / (1.f + __expf(-(cg[0] + cg[1] + bg[0])));
  float inv = 1.f / (cs[0] + cs[1]);
  if (tid < wlen) {
    float val = p * inv * gateval * mem_scale[0];
    int id = ids[b * L_SZ + w0 + tid];
    atomicAdd(&out[(size_t)bi * VCAB + id], val);
  }
}

// ---------------- launch ----------------
extern "C" void kernel_launch(void* const* d_in, const int* in_sizes, int n_in,
                              void* d_out, int out_size, void* d_ws, size_t ws_size,
                              hipStream_t stream) {
  (void)in_sizes; (void)n_in; (void)out_size; (void)ws_size;
  const int* ids = (const int*)d_in[0];
  const float* emb = (const float*)d_in[1];
  const float* w_ih = (const float*)d_in[2];
  const float* w_hh = (const float*)d_in[3];
  const float* b_ih = (const float*)d_in[4];
  const float* b_hh = (const float*)d_in[5];
  const float* wq = (const float*)d_in[6];
  const float* bq = (const float*)d_in[7];
  const float* wk = (const float*)d_in[8];
  const float* bk = (const float*)d_in[9];
  const float* wg = (const float*)d_in[10];
  const float* bg = (const float*)d_in[11];
  const float* wh = (const float*)d_in[12];
  const float* bh = (const float*)d_in[13];
  const float* outb = (const float*)d_in[14];
  const float* memsc = (const float*)d_in[15];
  float* out = (float*)d_out;

  char* ws = (char*)d_ws;
  size_t off = 0;
  auto alloc = [&](size_t bytes) {
    void* p = ws + off;
    off = (off + bytes + 255) & ~(size_t)255;
    return p;
  };
  unsigned long long* bcast = (unsigned long long*)alloc((size_t)NGRP * 2 * 512 * 8);
  float* gx = (float*)alloc((size_t)4096 * 1536 * 4);
  float* biascat = (float*)alloc(512 * 4);
  float* qkcat = (float*)alloc((size_t)4096 * 512 * 4);
  __half* embH = (__half*)alloc((size_t)VCAB * 256 * 2);
  __half* w_ihH = (__half*)alloc((size_t)1536 * 256 * 2);
  __half* statesH = (__half*)alloc((size_t)4096 * 512 * 2);
  __half* WcatH = (__half*)alloc((size_t)512 * 512 * 2);
  __half* qkcatH = (__half*)alloc((size_t)4096 * 512 * 2);

  hipMemsetAsync(bcast, 0, (size_t)NGRP * 2 * 512 * 8, stream);
  conv_f16_kernel<<<(VCAB * 256 / 4 + 255) / 256, 256, 0, stream>>>(emb, embH, VCAB * 256 / 4);
  conv_f16_kernel<<<(1536 * 256 / 4 + 255) / 256, 256, 0, stream>>>(w_ih, w_ihH, 1536 * 256 / 4);
  prep_kernel<<<256, 256, 0, stream>>>(wq, wk, wh, bq, bk, bh, WcatH, biascat);
  // gx = emb[ids] @ w_ih^T + b_ih
  mfma_gemm_kernel<<<dim3(1536 / 128, 4096 / 128), 256, 0, stream>>>(
      embH, w_ihH, b_ih, gx, nullptr, 4096, 1536, 256, 256, 1536, ids);
  gru_kernel<<<NGRP * GRU_WGS, 512, 0, stream>>>(gx, w_hh, b_hh, statesH, bcast);
  // fused q|k|h_emb projection: qkcat f32 (q,k) + qkcatH f16 (h_emb for base GEMM)
  mfma_gemm_kernel<<<dim3(512 / 128, 4096 / 128), 256, 0, stream>>>(
      statesH, WcatH, biascat, qkcat, qkcatH, 4096, 512, 512, 512, 512, nullptr);
  // base logits: A = h_emb slice of qkcatH (cols 256..511, row stride 512)
  mfma_gemm_kernel<<<dim3(VCAB / 128, 4096 / 128), 256, 0, stream>>>(
      qkcatH + 256, embH, outb, out, nullptr, 4096, VCAB, 256, 512, VCAB, nullptr);
  attn_kernel<<<4096, 128, 0, stream>>>(qkcat, statesH, wg, bg, ids, memsc, out);
}